// Round 1
// baseline (471.201 us; speedup 1.0000x reference)
//
#include <hip/hip_runtime.h>
#include <hip/hip_bf16.h>
#include <math.h>

#define B 16
#define T 4096
#define E 64
#define H 8
#define KP 256
#define GADD 8
#define RADD 8
#define REGION 64
#define VS (KP * (4 + GADD + RADD))   // 5120
#define NH (H * E)                    // 512

__device__ inline ushort f2bf(float f) {
    union { __hip_bfloat16 h; ushort u; } cv;
    cv.h = __float2bfloat16(f);
    return cv.u;
}

// ---- K points: flip -> sigmoid*(t-1) means; softplus sigmas ----
__global__ void k_points(const float* __restrict__ means_p, const float* __restrict__ sigmas_p,
                         float* __restrict__ meansf, float* __restrict__ sigt) {
    int k = threadIdx.x;
    if (k >= KP) return;
    float a = means_p[2 * k], b = means_p[2 * k + 1];
    float hi = fmaxf(a, b), lo = fminf(a, b);
    meansf[2 * k]     = (1.f / (1.f + expf(-hi))) * (float)(T - 1);
    meansf[2 * k + 1] = (1.f / (1.f + expf(-lo))) * (float)(T - 1);
    float sp = sigmas_p[k] + 2.0f;                       // SIGMA_BOOST
    float s = (sp > 20.f) ? sp : log1pf(expf(sp));       // softplus
    sigt[k] = (s + 0.05f) * (float)T;                    // (+MIN_SIGMA)*T*SIGMA_SCALE
}

// ---- Wvu_h = Wv_h @ Wu_h  (fold output projection into V) ----
__global__ void k_wvu(const float* __restrict__ Wv, const float* __restrict__ Wu,
                      float* __restrict__ Wvu) {
    int idx = blockIdx.x * blockDim.x + threadIdx.x;
    if (idx >= E * NH) return;
    int i = idx / NH, c = idx % NH;
    int h = c / E, j = c % E;
    float acc = 0.f;
    for (int d = 0; d < E; ++d)
        acc += Wv[i * NH + h * E + d] * Wu[(h * E + d) * E + j];
    Wvu[i * NH + c] = acc;
}

// ---- build sparse index tuples (flipped: row >= col) ----
__global__ void k_build_idx(const int* __restrict__ g_ints, const int* __restrict__ l_offs,
                            const float* __restrict__ meansf,
                            int* __restrict__ idxrow, int* __restrict__ idxcol) {
    int b = blockIdx.x;
    for (int s = threadIdx.x; s < VS; s += blockDim.x) {
        int k = s / 20, slot = s % 20;
        float m0 = meansf[2 * k], m1 = meansf[2 * k + 1];
        int i0, i1;
        if (slot < 4) {
            float a  = (slot & 2) ? ceilf(m0) : floorf(m0);
            float bb = (slot & 1) ? ceilf(m1) : floorf(m1);
            a  = fminf(fmaxf(a, 0.f), (float)(T - 1));
            bb = fminf(fmaxf(bb, 0.f), (float)(T - 1));
            i0 = (int)a; i1 = (int)bb;
        } else if (slot < 12) {
            const int* p = g_ints + ((size_t)((b * KP + k) * GADD) + (slot - 4)) * 2;
            i0 = p[0]; i1 = p[1];
        } else {
            int lo0 = (int)fminf(fmaxf(floorf(m0) - (float)(REGION / 2), 0.f), (float)(T - REGION));
            int lo1 = (int)fminf(fmaxf(floorf(m1) - (float)(REGION / 2), 0.f), (float)(T - REGION));
            const int* p = l_offs + ((size_t)((b * KP + k) * RADD) + (slot - 12)) * 2;
            i0 = lo0 + p[0]; i1 = lo1 + p[1];
        }
        int row = max(i0, i1), col = min(i0, i1);
        idxrow[b * VS + s] = row;
        idxcol[b * VS + s] = col;
    }
}

// ---- stable duplicate mask + within-row rank (deterministic) ----
__global__ __launch_bounds__(1024) void k_dup_rank(const int* __restrict__ idxrow,
                                                   const int* __restrict__ idxcol,
                                                   int* __restrict__ rank, int* __restrict__ dup) {
    int b = blockIdx.y, jb = blockIdx.x;   // jb in [0,5)
    __shared__ int srow[VS];
    __shared__ int sid[VS];
    for (int s = threadIdx.x; s < VS; s += 1024) {
        int r = idxrow[b * VS + s], c = idxcol[b * VS + s];
        srow[s] = r;
        sid[s] = r * T + c;
    }
    __syncthreads();
    int s = threadIdx.x * 5 + jb;
    int r = srow[s], id = sid[s];
    int rk = 0, dp = 0;
    for (int t = 0; t < s; ++t) {
        rk += (srow[t] == r);
        dp |= (sid[t] == id);
    }
    rank[b * VS + s] = rk;
    dup[b * VS + s] = dp;
}

// ---- column sums of the (non-dup) density matrix ----
__global__ void k_colsum(const int* __restrict__ idxrow, const int* __restrict__ idxcol,
                         const int* __restrict__ dup, const float* __restrict__ meansf,
                         const float* __restrict__ sigt, float* __restrict__ colsum) {
    int k = blockIdx.x, b = blockIdx.y;
    float m0 = meansf[2 * k], m1 = meansf[2 * k + 1];
    float inv = 1.f / sigt[k];
    float acc = 0.f;
    for (int s = threadIdx.x; s < VS; s += 256) {
        if (!dup[b * VS + s]) {
            float d0 = ((float)idxrow[b * VS + s] - m0) * inv;
            float d1 = ((float)idxcol[b * VS + s] - m1) * inv;
            acc += __expf(-0.5f * (d0 * d0 + d1 * d1));
        }
    }
    __shared__ float red[256];
    red[threadIdx.x] = acc;
    __syncthreads();
    for (int o = 128; o > 0; o >>= 1) {
        if (threadIdx.x < o) red[threadIdx.x] += red[threadIdx.x + o];
        __syncthreads();
    }
    if (threadIdx.x == 0) colsum[b * KP + k] = red[0];
}

// ---- per-entry weight = sum_k prop/colsum_k ----
__global__ void k_weights(const int* __restrict__ idxrow, const int* __restrict__ idxcol,
                          const int* __restrict__ dup, const float* __restrict__ meansf,
                          const float* __restrict__ sigt, const float* __restrict__ colsum,
                          float* __restrict__ wts) {
    int b = blockIdx.y;
    int s = blockIdx.x * 256 + threadIdx.x;
    __shared__ float sm[2 * KP], ss[KP], rc[KP];
    for (int k = threadIdx.x; k < KP; k += 256) {
        sm[2 * k] = meansf[2 * k];
        sm[2 * k + 1] = meansf[2 * k + 1];
        ss[k] = 1.f / sigt[k];
        rc[k] = 1.f / colsum[b * KP + k];
    }
    __syncthreads();
    float w = 0.f;
    if (!dup[b * VS + s]) {
        float r = (float)idxrow[b * VS + s], c = (float)idxcol[b * VS + s];
        #pragma unroll 4
        for (int k = 0; k < KP; ++k) {
            float d0 = (r - sm[2 * k]) * ss[k];
            float d1 = (c - sm[2 * k + 1]) * ss[k];
            w += __expf(-0.5f * (d0 * d0 + d1 * d1)) * rc[k];
        }
    }
    wts[b * VS + s] = w;
}

// ---- row histogram ----
__global__ void k_count(const int* __restrict__ idxrow, int* __restrict__ rowcnt) {
    int b = blockIdx.y;
    int s = blockIdx.x * 256 + threadIdx.x;
    atomicAdd(&rowcnt[b * T + idxrow[b * VS + s]], 1);
}

// ---- exclusive prefix sum per batch (4096 rows) ----
__global__ __launch_bounds__(1024) void k_scan(const int* __restrict__ rowcnt, int* __restrict__ rowptr) {
    int b = blockIdx.x, tid = threadIdx.x;
    __shared__ int part[1024];
    int v[4]; int loc = 0;
    for (int j = 0; j < 4; ++j) { v[j] = rowcnt[b * T + tid * 4 + j]; loc += v[j]; }
    part[tid] = loc;
    __syncthreads();
    for (int off = 1; off < 1024; off <<= 1) {
        int t = (tid >= off) ? part[tid - off] : 0;
        __syncthreads();
        part[tid] += t;
        __syncthreads();
    }
    int excl = part[tid] - loc;
    for (int j = 0; j < 4; ++j) { rowptr[b * (T + 1) + tid * 4 + j] = excl; excl += v[j]; }
    if (tid == 1023) rowptr[b * (T + 1) + T] = part[1023];
}

// ---- deterministic counting-sort scatter ----
__global__ void k_scatter(const int* __restrict__ idxrow, const int* __restrict__ idxcol,
                          const float* __restrict__ wts, const int* __restrict__ rank,
                          const int* __restrict__ rowptr,
                          int* __restrict__ scol, float* __restrict__ sw) {
    int b = blockIdx.y;
    int s = blockIdx.x * 256 + threadIdx.x;
    int r = idxrow[b * VS + s];
    int pos = rowptr[b * (T + 1) + r] + rank[b * VS + s];
    scol[b * VS + pos] = idxcol[b * VS + s];
    sw[b * VS + pos] = wts[b * VS + s];
}

// ---- projections: out = x @ W, stored bf16. z selects {Wq->q, Wk->k, Wvu->vu} ----
#define GT_M 64
#define GT_N 128
__global__ __launch_bounds__(256) void k_gemm(const float* __restrict__ x,
        const float* __restrict__ Wq, const float* __restrict__ Wk, const float* __restrict__ Wvu,
        __hip_bfloat16* __restrict__ q, __hip_bfloat16* __restrict__ kk, __hip_bfloat16* __restrict__ vu) {
    const float* W; __hip_bfloat16* outp;
    if (blockIdx.z == 0)      { W = Wq;  outp = q;  }
    else if (blockIdx.z == 1) { W = Wk;  outp = kk; }
    else                      { W = Wvu; outp = vu; }
    __shared__ float xs[GT_M * 64];
    __shared__ float ws[64 * GT_N];
    int row0 = blockIdx.x * GT_M, col0 = blockIdx.y * GT_N;
    int tid = threadIdx.x;
    for (int t4 = tid; t4 < GT_M * 16; t4 += 256) {
        int r = t4 >> 4, c = t4 & 15;
        ((float4*)xs)[t4] = *(const float4*)(x + (size_t)(row0 + r) * 64 + c * 4);
    }
    for (int t4 = tid; t4 < 64 * (GT_N / 4); t4 += 256) {
        int r = t4 / (GT_N / 4), c = t4 % (GT_N / 4);
        ((float4*)ws)[t4] = *(const float4*)(W + (size_t)r * NH + col0 + c * 4);
    }
    __syncthreads();
    int tx = tid & 31, ty = tid >> 5;
    float acc[8][4] = {};
    for (int i = 0; i < 64; ++i) {
        float xv[8];
        #pragma unroll
        for (int u = 0; u < 8; ++u) xv[u] = xs[(ty * 8 + u) * 64 + i];
        float4 w4 = *(float4*)&ws[i * GT_N + tx * 4];
        float wv[4] = { w4.x, w4.y, w4.z, w4.w };
        #pragma unroll
        for (int u = 0; u < 8; ++u)
            #pragma unroll
            for (int v = 0; v < 4; ++v) acc[u][v] += xv[u] * wv[v];
    }
    #pragma unroll
    for (int u = 0; u < 8; ++u) {
        int r = row0 + ty * 8 + u;
        uint32_t lo = (uint32_t)f2bf(acc[u][0]) | ((uint32_t)f2bf(acc[u][1]) << 16);
        uint32_t hi = (uint32_t)f2bf(acc[u][2]) | ((uint32_t)f2bf(acc[u][3]) << 16);
        *(uint2*)(outp + (size_t)r * NH + col0 + tx * 4) = make_uint2(lo, hi);
    }
}

// ---- per-row online-softmax attention + folded output projection ----
__global__ __launch_bounds__(256) void k_attn(
        const __hip_bfloat16* __restrict__ q, const __hip_bfloat16* __restrict__ kk,
        const __hip_bfloat16* __restrict__ vu, const int* __restrict__ rowptr,
        const int* __restrict__ scol, const float* __restrict__ sw,
        const float* __restrict__ bu, float* __restrict__ out) {
    int gr = blockIdx.x;                 // b*T + r
    int b = gr >> 12;
    int r = gr & (T - 1);
    int lane = threadIdx.x & 63, wv = threadIdx.x >> 6;
    int p0 = rowptr[b * (T + 1) + r], p1 = rowptr[b * (T + 1) + r + 1];
    __shared__ float sacc[4][64];
    float acc = 0.f;
    for (int h = wv; h < H; h += 4) {
        float qv = __bfloat162float(q[(size_t)gr * NH + h * E + lane]);
        float m = -INFINITY, ssum = 0.f, av = 0.f;
        for (int e = p0; e < p1; ++e) {
            int c = scol[b * VS + e];
            float w = sw[b * VS + e];
            float kv = __bfloat162float(kk[((size_t)(b * T + c)) * NH + h * E + lane]);
            float prod = qv * kv;
            #pragma unroll
            for (int o = 32; o; o >>= 1) prod += __shfl_xor(prod, o);
            float d = 0.125f * w * prod;                 // (e^-0.25)^2 = 1/8
            float nm = fmaxf(m, d);
            float corr = __expf(m - nm);                 // 0 on first entry (m=-inf)
            float t = __expf(d - nm);
            float vval = __bfloat162float(vu[((size_t)(b * T + c)) * NH + h * E + lane]);
            ssum = ssum * corr + t;
            av = av * corr + t * vval;
            m = nm;
        }
        if (p1 > p0) acc += av / ssum;
    }
    sacc[wv][lane] = acc;
    __syncthreads();
    if (wv == 0) {
        float o = sacc[0][lane] + sacc[1][lane] + sacc[2][lane] + sacc[3][lane] + bu[lane];
        out[(size_t)gr * E + lane] = o;
    }
}

extern "C" void kernel_launch(void* const* d_in, const int* in_sizes, int n_in,
                              void* d_out, int out_size, void* d_ws, size_t ws_size,
                              hipStream_t stream) {
    const float* x        = (const float*)d_in[0];
    const float* Wq       = (const float*)d_in[1];
    const float* Wk       = (const float*)d_in[2];
    const float* Wv       = (const float*)d_in[3];
    const float* Wu       = (const float*)d_in[4];
    const float* bu       = (const float*)d_in[5];
    const float* means_p  = (const float*)d_in[6];
    const float* sigmas_p = (const float*)d_in[7];
    const int*   g_ints   = (const int*)d_in[8];
    const int*   l_offs   = (const int*)d_in[9];
    float* out = (float*)d_out;

    char* ws = (char*)d_ws;
    size_t o = 0;
    auto alloc = [&](size_t bytes) -> void* {
        void* p = ws + o;
        o += (bytes + 255) & ~(size_t)255;
        return p;
    };
    __hip_bfloat16* q   = (__hip_bfloat16*)alloc((size_t)B * T * NH * 2);
    __hip_bfloat16* kk  = (__hip_bfloat16*)alloc((size_t)B * T * NH * 2);
    __hip_bfloat16* vu  = (__hip_bfloat16*)alloc((size_t)B * T * NH * 2);
    float* Wvu    = (float*)alloc((size_t)E * NH * 4);
    float* meansf = (float*)alloc(KP * 2 * 4);
    float* sigt   = (float*)alloc(KP * 4);
    int*   idxrow = (int*)alloc((size_t)B * VS * 4);
    int*   idxcol = (int*)alloc((size_t)B * VS * 4);
    float* wts    = (float*)alloc((size_t)B * VS * 4);
    int*   rank   = (int*)alloc((size_t)B * VS * 4);
    int*   dup    = (int*)alloc((size_t)B * VS * 4);
    float* colsum = (float*)alloc((size_t)B * KP * 4);
    int*   rowcnt = (int*)alloc((size_t)B * T * 4);
    int*   rowptr = (int*)alloc((size_t)B * (T + 1) * 4);
    int*   scol   = (int*)alloc((size_t)B * VS * 4);
    float* sw     = (float*)alloc((size_t)B * VS * 4);

    hipMemsetAsync(rowcnt, 0, (size_t)B * T * 4, stream);

    k_points<<<1, 256, 0, stream>>>(means_p, sigmas_p, meansf, sigt);
    k_wvu<<<(E * NH + 255) / 256, 256, 0, stream>>>(Wv, Wu, Wvu);
    k_build_idx<<<B, 256, 0, stream>>>(g_ints, l_offs, meansf, idxrow, idxcol);
    k_dup_rank<<<dim3(5, B), 1024, 0, stream>>>(idxrow, idxcol, rank, dup);
    k_colsum<<<dim3(KP, B), 256, 0, stream>>>(idxrow, idxcol, dup, meansf, sigt, colsum);
    k_weights<<<dim3(VS / 256, B), 256, 0, stream>>>(idxrow, idxcol, dup, meansf, sigt, colsum, wts);
    k_count<<<dim3(VS / 256, B), 256, 0, stream>>>(idxrow, rowcnt);
    k_scan<<<B, 1024, 0, stream>>>(rowcnt, rowptr);
    k_scatter<<<dim3(VS / 256, B), 256, 0, stream>>>(idxrow, idxcol, wts, rank, rowptr, scol, sw);
    k_gemm<<<dim3(B * T / GT_M, NH / GT_N, 3), 256, 0, stream>>>(x, Wq, Wk, Wvu, q, kk, vu);
    k_attn<<<B * T, 256, 0, stream>>>(q, kk, vu, rowptr, scol, sw, bu, out);
}

// Round 2
// 328.536 us; speedup vs baseline: 1.4342x; 1.4342x over previous
//
#include <hip/hip_runtime.h>
#include <hip/hip_bf16.h>
#include <math.h>

#define B 16
#define T 4096
#define E 64
#define H 8
#define KP 256
#define GADD 8
#define RADD 8
#define REGION 64
#define VS (KP * (4 + GADD + RADD))   // 5120
#define NH (H * E)                    // 512

typedef __attribute__((ext_vector_type(8))) short bf16x8;
typedef __attribute__((ext_vector_type(4))) float f32x4;

__device__ inline ushort f2bf(float f) {
    union { __hip_bfloat16 h; ushort u; } cv;
    cv.h = __float2bfloat16(f);
    return cv.u;
}
__device__ inline float bflo(uint32_t p) { return __uint_as_float(p << 16); }
__device__ inline float bfhi(uint32_t p) { return __uint_as_float(p & 0xffff0000u); }

// ---- K points: flip -> sigmoid*(t-1) means; softplus sigmas ----
__global__ void k_points(const float* __restrict__ means_p, const float* __restrict__ sigmas_p,
                         float* __restrict__ meansf, float* __restrict__ sigt) {
    int k = threadIdx.x;
    if (k >= KP) return;
    float a = means_p[2 * k], b = means_p[2 * k + 1];
    float hi = fmaxf(a, b), lo = fminf(a, b);
    meansf[2 * k]     = (1.f / (1.f + expf(-hi))) * (float)(T - 1);
    meansf[2 * k + 1] = (1.f / (1.f + expf(-lo))) * (float)(T - 1);
    float sp = sigmas_p[k] + 2.0f;
    float s = (sp > 20.f) ? sp : log1pf(expf(sp));
    sigt[k] = (s + 0.05f) * (float)T;
}

// ---- Wvu_h = Wv_h @ Wu_h  (fold output projection into V) ----
__global__ void k_wvu(const float* __restrict__ Wv, const float* __restrict__ Wu,
                      float* __restrict__ Wvu) {
    int idx = blockIdx.x * blockDim.x + threadIdx.x;
    if (idx >= E * NH) return;
    int i = idx / NH, c = idx % NH;
    int h = c / E, j = c % E;
    float acc = 0.f;
    for (int d = 0; d < E; ++d)
        acc += Wv[i * NH + h * E + d] * Wu[(h * E + d) * E + j];
    Wvu[i * NH + c] = acc;
}

// ---- x f32 -> bf16 ----
__global__ void k_prep_x(const float* __restrict__ x, ushort* __restrict__ xb) {
    int i = (blockIdx.x * 256 + threadIdx.x) * 8;
    float4 a = *(const float4*)(x + i);
    float4 b = *(const float4*)(x + i + 4);
    uint4 r;
    r.x = (uint32_t)f2bf(a.x) | ((uint32_t)f2bf(a.y) << 16);
    r.y = (uint32_t)f2bf(a.z) | ((uint32_t)f2bf(a.w) << 16);
    r.z = (uint32_t)f2bf(b.x) | ((uint32_t)f2bf(b.y) << 16);
    r.w = (uint32_t)f2bf(b.z) | ((uint32_t)f2bf(b.w) << 16);
    *(uint4*)(xb + i) = r;
}

// ---- pre-pack W into MFMA B-fragment lane order (bf16) ----
// layout: wfrag[ (((z*32 + nf)*2 + kf)*64 + lane)*8 + j ]  <- W_z[(kf*32+(lane>>4)*8+j)*512 + nf*16 + (lane&15)]
__global__ void k_prep_w(const float* __restrict__ Wq, const float* __restrict__ Wk,
                         const float* __restrict__ Wvu, ushort* __restrict__ wfrag) {
    int t = blockIdx.x * 256 + threadIdx.x;
    if (t >= 3 * 32 * 2 * 64) return;
    int lane = t & 63, kf = (t >> 6) & 1, nf = (t >> 7) & 31, z = t >> 12;
    const float* W = (z == 0) ? Wq : (z == 1) ? Wk : Wvu;
    int col = nf * 16 + (lane & 15);
    int krow = kf * 32 + (lane >> 4) * 8;
    uint4 r;
    uint32_t v[8];
    #pragma unroll
    for (int j = 0; j < 8; ++j) v[j] = f2bf(W[(size_t)(krow + j) * NH + col]);
    r.x = v[0] | (v[1] << 16); r.y = v[2] | (v[3] << 16);
    r.z = v[4] | (v[5] << 16); r.w = v[6] | (v[7] << 16);
    *(uint4*)(wfrag + (size_t)t * 8) = r;
}

// ---- MFMA projection: out_z = xb @ W_z, bf16, no LDS ----
__global__ __launch_bounds__(256) void k_proj(const ushort* __restrict__ xb,
        const ushort* __restrict__ wfrag,
        __hip_bfloat16* __restrict__ q, __hip_bfloat16* __restrict__ kk,
        __hip_bfloat16* __restrict__ vu) {
    int z = blockIdx.y;
    __hip_bfloat16* outp = (z == 0) ? q : (z == 1) ? kk : vu;
    int row0 = blockIdx.x * 64;
    int wv = threadIdx.x >> 6, lane = threadIdx.x & 63;
    int arow = lane & 15, akoff = (lane >> 4) * 8;

    bf16x8 a[4][2];
    #pragma unroll
    for (int mf = 0; mf < 4; ++mf)
        #pragma unroll
        for (int kf = 0; kf < 2; ++kf)
            a[mf][kf] = *(const bf16x8*)(xb + (size_t)(row0 + mf * 16 + arow) * 64 + kf * 32 + akoff);

    #pragma unroll
    for (int nf = 0; nf < 8; ++nf) {
        size_t base = ((size_t)((z * 32 + wv * 8 + nf) * 2) * 64 + lane) * 8;
        bf16x8 b0 = *(const bf16x8*)(wfrag + base);
        bf16x8 b1 = *(const bf16x8*)(wfrag + base + 64 * 8);
        int col = wv * 128 + nf * 16 + (lane & 15);
        #pragma unroll
        for (int mf = 0; mf < 4; ++mf) {
            f32x4 acc = {0.f, 0.f, 0.f, 0.f};
            acc = __builtin_amdgcn_mfma_f32_16x16x32_bf16(a[mf][0], b0, acc, 0, 0, 0);
            acc = __builtin_amdgcn_mfma_f32_16x16x32_bf16(a[mf][1], b1, acc, 0, 0, 0);
            int rbase = row0 + mf * 16 + (lane >> 4) * 4;
            #pragma unroll
            for (int rg = 0; rg < 4; ++rg)
                outp[(size_t)(rbase + rg) * NH + col] = __float2bfloat16(acc[rg]);
        }
    }
}

// ---- build sparse index tuples (flipped: row >= col) ----
__global__ void k_build_idx(const int* __restrict__ g_ints, const int* __restrict__ l_offs,
                            const float* __restrict__ meansf,
                            int* __restrict__ idxrow, int* __restrict__ idxcol) {
    int b = blockIdx.x;
    for (int s = threadIdx.x; s < VS; s += blockDim.x) {
        int k = s / 20, slot = s % 20;
        float m0 = meansf[2 * k], m1 = meansf[2 * k + 1];
        int i0, i1;
        if (slot < 4) {
            float a  = (slot & 2) ? ceilf(m0) : floorf(m0);
            float bb = (slot & 1) ? ceilf(m1) : floorf(m1);
            a  = fminf(fmaxf(a, 0.f), (float)(T - 1));
            bb = fminf(fmaxf(bb, 0.f), (float)(T - 1));
            i0 = (int)a; i1 = (int)bb;
        } else if (slot < 12) {
            const int* p = g_ints + ((size_t)((b * KP + k) * GADD) + (slot - 4)) * 2;
            i0 = p[0]; i1 = p[1];
        } else {
            int lo0 = (int)fminf(fmaxf(floorf(m0) - (float)(REGION / 2), 0.f), (float)(T - REGION));
            int lo1 = (int)fminf(fmaxf(floorf(m1) - (float)(REGION / 2), 0.f), (float)(T - REGION));
            const int* p = l_offs + ((size_t)((b * KP + k) * RADD) + (slot - 12)) * 2;
            i0 = lo0 + p[0]; i1 = lo1 + p[1];
        }
        int row = max(i0, i1), col = min(i0, i1);
        idxrow[b * VS + s] = row;
        idxcol[b * VS + s] = col;
    }
}

// ---- stable duplicate mask + within-row rank (deterministic) ----
__global__ __launch_bounds__(1024) void k_dup_rank(const int* __restrict__ idxrow,
                                                   const int* __restrict__ idxcol,
                                                   int* __restrict__ rank, int* __restrict__ dup) {
    int b = blockIdx.y, jb = blockIdx.x;   // jb in [0,5)
    __shared__ int srow[VS];
    __shared__ int sid[VS];
    for (int s = threadIdx.x; s < VS; s += 1024) {
        int r = idxrow[b * VS + s], c = idxcol[b * VS + s];
        srow[s] = r;
        sid[s] = r * T + c;
    }
    __syncthreads();
    int s = threadIdx.x * 5 + jb;
    int r = srow[s], id = sid[s];
    int rk = 0, dp = 0;
    for (int t = 0; t < s; ++t) {
        rk += (srow[t] == r);
        dp |= (sid[t] == id);
    }
    rank[b * VS + s] = rk;
    dup[b * VS + s] = dp;
}

// ---- column sums of the (non-dup) density matrix ----
__global__ void k_colsum(const int* __restrict__ idxrow, const int* __restrict__ idxcol,
                         const int* __restrict__ dup, const float* __restrict__ meansf,
                         const float* __restrict__ sigt, float* __restrict__ colsum) {
    int k = blockIdx.x, b = blockIdx.y;
    float m0 = meansf[2 * k], m1 = meansf[2 * k + 1];
    float inv = 1.f / sigt[k];
    float acc = 0.f;
    for (int s = threadIdx.x; s < VS; s += 256) {
        if (!dup[b * VS + s]) {
            float d0 = ((float)idxrow[b * VS + s] - m0) * inv;
            float d1 = ((float)idxcol[b * VS + s] - m1) * inv;
            acc += __expf(-0.5f * (d0 * d0 + d1 * d1));
        }
    }
    __shared__ float red[256];
    red[threadIdx.x] = acc;
    __syncthreads();
    for (int o = 128; o > 0; o >>= 1) {
        if (threadIdx.x < o) red[threadIdx.x] += red[threadIdx.x + o];
        __syncthreads();
    }
    if (threadIdx.x == 0) colsum[b * KP + k] = red[0];
}

// ---- per-entry weight = sum_k prop/colsum_k ----
__global__ void k_weights(const int* __restrict__ idxrow, const int* __restrict__ idxcol,
                          const int* __restrict__ dup, const float* __restrict__ meansf,
                          const float* __restrict__ sigt, const float* __restrict__ colsum,
                          float* __restrict__ wts) {
    int b = blockIdx.y;
    int s = blockIdx.x * 256 + threadIdx.x;
    __shared__ float sm[2 * KP], ss[KP], rc[KP];
    for (int k = threadIdx.x; k < KP; k += 256) {
        sm[2 * k] = meansf[2 * k];
        sm[2 * k + 1] = meansf[2 * k + 1];
        ss[k] = 1.f / sigt[k];
        rc[k] = 1.f / colsum[b * KP + k];
    }
    __syncthreads();
    float w = 0.f;
    if (!dup[b * VS + s]) {
        float r = (float)idxrow[b * VS + s], c = (float)idxcol[b * VS + s];
        #pragma unroll 4
        for (int k = 0; k < KP; ++k) {
            float d0 = (r - sm[2 * k]) * ss[k];
            float d1 = (c - sm[2 * k + 1]) * ss[k];
            w += __expf(-0.5f * (d0 * d0 + d1 * d1)) * rc[k];
        }
    }
    wts[b * VS + s] = w;
}

// ---- row histogram ----
__global__ void k_count(const int* __restrict__ idxrow, int* __restrict__ rowcnt) {
    int b = blockIdx.y;
    int s = blockIdx.x * 256 + threadIdx.x;
    atomicAdd(&rowcnt[b * T + idxrow[b * VS + s]], 1);
}

// ---- exclusive prefix sum per batch (4096 rows) ----
__global__ __launch_bounds__(1024) void k_scan(const int* __restrict__ rowcnt, int* __restrict__ rowptr) {
    int b = blockIdx.x, tid = threadIdx.x;
    __shared__ int part[1024];
    int v[4]; int loc = 0;
    for (int j = 0; j < 4; ++j) { v[j] = rowcnt[b * T + tid * 4 + j]; loc += v[j]; }
    part[tid] = loc;
    __syncthreads();
    for (int off = 1; off < 1024; off <<= 1) {
        int t = (tid >= off) ? part[tid - off] : 0;
        __syncthreads();
        part[tid] += t;
        __syncthreads();
    }
    int excl = part[tid] - loc;
    for (int j = 0; j < 4; ++j) { rowptr[b * (T + 1) + tid * 4 + j] = excl; excl += v[j]; }
    if (tid == 1023) rowptr[b * (T + 1) + T] = part[1023];
}

// ---- deterministic counting-sort scatter ----
__global__ void k_scatter(const int* __restrict__ idxrow, const int* __restrict__ idxcol,
                          const float* __restrict__ wts, const int* __restrict__ rank,
                          const int* __restrict__ rowptr,
                          int* __restrict__ scol, float* __restrict__ sw) {
    int b = blockIdx.y;
    int s = blockIdx.x * 256 + threadIdx.x;
    int r = idxrow[b * VS + s];
    int pos = rowptr[b * (T + 1) + r] + rank[b * VS + s];
    scol[b * VS + pos] = idxcol[b * VS + s];
    sw[b * VS + pos] = wts[b * VS + s];
}

// ---- attention: one wave per row, lane = head*8 + li, 8 feats/lane ----
__global__ __launch_bounds__(256) void k_attn(
        const __hip_bfloat16* __restrict__ q, const __hip_bfloat16* __restrict__ kk,
        const __hip_bfloat16* __restrict__ vu, const int* __restrict__ rowptr,
        const int* __restrict__ scol, const float* __restrict__ sw,
        const float* __restrict__ bu, float* __restrict__ out) {
    int gr = blockIdx.x * 4 + (threadIdx.x >> 6);   // b*T + r
    int b = gr >> 12;
    int r = gr & (T - 1);
    int lane = threadIdx.x & 63;
    int p0 = rowptr[b * (T + 1) + r], p1 = rowptr[b * (T + 1) + r + 1];

    uint4 q4 = *(const uint4*)((const ushort*)q + (size_t)gr * NH + lane * 8);
    float qv[8] = { bflo(q4.x), bfhi(q4.x), bflo(q4.y), bfhi(q4.y),
                    bflo(q4.z), bfhi(q4.z), bflo(q4.w), bfhi(q4.w) };

    float m = -INFINITY, ssum = 0.f;
    float av[8] = {0.f,0.f,0.f,0.f,0.f,0.f,0.f,0.f};

    for (int e = p0; e < p1; ++e) {
        int c = scol[b * VS + e];
        float w = sw[b * VS + e];
        size_t off = ((size_t)(b * T + c)) * NH + lane * 8;
        uint4 k4 = *(const uint4*)((const ushort*)kk + off);
        float dp = qv[0]*bflo(k4.x) + qv[1]*bfhi(k4.x) + qv[2]*bflo(k4.y) + qv[3]*bfhi(k4.y)
                 + qv[4]*bflo(k4.z) + qv[5]*bfhi(k4.z) + qv[6]*bflo(k4.w) + qv[7]*bfhi(k4.w);
        dp += __shfl_xor(dp, 1);
        dp += __shfl_xor(dp, 2);
        dp += __shfl_xor(dp, 4);
        float d = 0.125f * w * dp;                 // (e^-0.25)^2 = 1/8
        float nm = fmaxf(m, d);
        float corr = __expf(m - nm);
        float t = __expf(d - nm);
        uint4 v4 = *(const uint4*)((const ushort*)vu + off);
        float vf[8] = { bflo(v4.x), bfhi(v4.x), bflo(v4.y), bfhi(v4.y),
                        bflo(v4.z), bfhi(v4.z), bflo(v4.w), bfhi(v4.w) };
        ssum = ssum * corr + t;
        #pragma unroll
        for (int u = 0; u < 8; ++u) av[u] = av[u] * corr + t * vf[u];
        m = nm;
    }

    float inv = (p1 > p0) ? (1.f / ssum) : 0.f;
    float res[8];
    #pragma unroll
    for (int u = 0; u < 8; ++u) {
        float v = av[u] * inv;
        v += __shfl_xor(v, 8);
        v += __shfl_xor(v, 16);
        v += __shfl_xor(v, 32);
        res[u] = v;
    }
    if (lane < 8) {
        float4 o0 = make_float4(res[0] + bu[lane*8+0], res[1] + bu[lane*8+1],
                                res[2] + bu[lane*8+2], res[3] + bu[lane*8+3]);
        float4 o1 = make_float4(res[4] + bu[lane*8+4], res[5] + bu[lane*8+5],
                                res[6] + bu[lane*8+6], res[7] + bu[lane*8+7]);
        *(float4*)(out + (size_t)gr * E + lane * 8)     = o0;
        *(float4*)(out + (size_t)gr * E + lane * 8 + 4) = o1;
    }
}

extern "C" void kernel_launch(void* const* d_in, const int* in_sizes, int n_in,
                              void* d_out, int out_size, void* d_ws, size_t ws_size,
                              hipStream_t stream) {
    const float* x        = (const float*)d_in[0];
    const float* Wq       = (const float*)d_in[1];
    const float* Wk       = (const float*)d_in[2];
    const float* Wv       = (const float*)d_in[3];
    const float* Wu       = (const float*)d_in[4];
    const float* bu       = (const float*)d_in[5];
    const float* means_p  = (const float*)d_in[6];
    const float* sigmas_p = (const float*)d_in[7];
    const int*   g_ints   = (const int*)d_in[8];
    const int*   l_offs   = (const int*)d_in[9];
    float* out = (float*)d_out;

    char* ws = (char*)d_ws;
    size_t o = 0;
    auto alloc = [&](size_t bytes) -> void* {
        void* p = ws + o;
        o += (bytes + 255) & ~(size_t)255;
        return p;
    };
    __hip_bfloat16* q   = (__hip_bfloat16*)alloc((size_t)B * T * NH * 2);
    __hip_bfloat16* kk  = (__hip_bfloat16*)alloc((size_t)B * T * NH * 2);
    __hip_bfloat16* vu  = (__hip_bfloat16*)alloc((size_t)B * T * NH * 2);
    ushort* xb    = (ushort*)alloc((size_t)B * T * E * 2);
    ushort* wfrag = (ushort*)alloc((size_t)3 * 32 * 2 * 64 * 8 * 2);
    float* Wvu    = (float*)alloc((size_t)E * NH * 4);
    float* meansf = (float*)alloc(KP * 2 * 4);
    float* sigt   = (float*)alloc(KP * 4);
    int*   idxrow = (int*)alloc((size_t)B * VS * 4);
    int*   idxcol = (int*)alloc((size_t)B * VS * 4);
    float* wts    = (float*)alloc((size_t)B * VS * 4);
    int*   rank   = (int*)alloc((size_t)B * VS * 4);
    int*   dup    = (int*)alloc((size_t)B * VS * 4);
    float* colsum = (float*)alloc((size_t)B * KP * 4);
    int*   rowcnt = (int*)alloc((size_t)B * T * 4);
    int*   rowptr = (int*)alloc((size_t)B * (T + 1) * 4);
    int*   scol   = (int*)alloc((size_t)B * VS * 4);
    float* sw     = (float*)alloc((size_t)B * VS * 4);

    hipMemsetAsync(rowcnt, 0, (size_t)B * T * 4, stream);

    k_points<<<1, 256, 0, stream>>>(means_p, sigmas_p, meansf, sigt);
    k_wvu<<<(E * NH + 255) / 256, 256, 0, stream>>>(Wv, Wu, Wvu);
    k_prep_x<<<(B * T * E / 8) / 256, 256, 0, stream>>>(x, xb);
    k_prep_w<<<(3 * 32 * 2 * 64 + 255) / 256, 256, 0, stream>>>(Wq, Wk, Wvu, wfrag);
    k_build_idx<<<B, 256, 0, stream>>>(g_ints, l_offs, meansf, idxrow, idxcol);
    k_dup_rank<<<dim3(5, B), 1024, 0, stream>>>(idxrow, idxcol, rank, dup);
    k_colsum<<<dim3(KP, B), 256, 0, stream>>>(idxrow, idxcol, dup, meansf, sigt, colsum);
    k_weights<<<dim3(VS / 256, B), 256, 0, stream>>>(idxrow, idxcol, dup, meansf, sigt, colsum, wts);
    k_count<<<dim3(VS / 256, B), 256, 0, stream>>>(idxrow, rowcnt);
    k_scan<<<B, 1024, 0, stream>>>(rowcnt, rowptr);
    k_scatter<<<dim3(VS / 256, B), 256, 0, stream>>>(idxrow, idxcol, wts, rank, rowptr, scol, sw);
    k_proj<<<dim3(B * T / 64, 3), 256, 0, stream>>>(xb, wfrag, q, kk, vu);
    k_attn<<<B * T / 4, 256, 0, stream>>>(q, kk, vu, rowptr, scol, sw, bu, out);
}

// Round 3
// 269.610 us; speedup vs baseline: 1.7477x; 1.2186x over previous
//
#include <hip/hip_runtime.h>
#include <hip/hip_bf16.h>
#include <math.h>

#define B 16
#define T 4096
#define E 64
#define H 8
#define KP 256
#define GADD 8
#define RADD 8
#define REGION 64
#define VS (KP * (4 + GADD + RADD))   // 5120
#define NH (H * E)                    // 512
#define NCHUNK 20                     // VS / 256
#define HSZ 16384                     // hash slots per batch

typedef __attribute__((ext_vector_type(8))) short bf16x8;
typedef __attribute__((ext_vector_type(4))) float f32x4;

__device__ inline ushort f2bf(float f) {
    union { __hip_bfloat16 h; ushort u; } cv;
    cv.h = __float2bfloat16(f);
    return cv.u;
}
__device__ inline float bflo(uint32_t p) { return __uint_as_float(p << 16); }
__device__ inline float bfhi(uint32_t p) { return __uint_as_float(p & 0xffff0000u); }

// ---- K points: flip -> sigmoid*(t-1) means; softplus sigmas ----
__global__ void k_points(const float* __restrict__ means_p, const float* __restrict__ sigmas_p,
                         float* __restrict__ meansf, float* __restrict__ sigt) {
    int k = threadIdx.x;
    if (k >= KP) return;
    float a = means_p[2 * k], b = means_p[2 * k + 1];
    float hi = fmaxf(a, b), lo = fminf(a, b);
    meansf[2 * k]     = (1.f / (1.f + expf(-hi))) * (float)(T - 1);
    meansf[2 * k + 1] = (1.f / (1.f + expf(-lo))) * (float)(T - 1);
    float sp = sigmas_p[k] + 2.0f;
    float s = (sp > 20.f) ? sp : log1pf(expf(sp));
    sigt[k] = (s + 0.05f) * (float)T;
}

// ---- Wvu_h = Wv_h @ Wu_h  (fold output projection into V) ----
__global__ void k_wvu(const float* __restrict__ Wv, const float* __restrict__ Wu,
                      float* __restrict__ Wvu) {
    int idx = blockIdx.x * blockDim.x + threadIdx.x;
    if (idx >= E * NH) return;
    int i = idx / NH, c = idx % NH;
    int h = c / E, j = c % E;
    float acc = 0.f;
    for (int d = 0; d < E; ++d)
        acc += Wv[i * NH + h * E + d] * Wu[(h * E + d) * E + j];
    Wvu[i * NH + c] = acc;
}

// ---- x f32 -> bf16 ----
__global__ void k_prep_x(const float* __restrict__ x, ushort* __restrict__ xb) {
    int i = (blockIdx.x * 256 + threadIdx.x) * 8;
    float4 a = *(const float4*)(x + i);
    float4 b = *(const float4*)(x + i + 4);
    uint4 r;
    r.x = (uint32_t)f2bf(a.x) | ((uint32_t)f2bf(a.y) << 16);
    r.y = (uint32_t)f2bf(a.z) | ((uint32_t)f2bf(a.w) << 16);
    r.z = (uint32_t)f2bf(b.x) | ((uint32_t)f2bf(b.y) << 16);
    r.w = (uint32_t)f2bf(b.z) | ((uint32_t)f2bf(b.w) << 16);
    *(uint4*)(xb + i) = r;
}

// ---- pre-pack W into MFMA B-fragment lane order (bf16) ----
__global__ void k_prep_w(const float* __restrict__ Wq, const float* __restrict__ Wk,
                         const float* __restrict__ Wvu, ushort* __restrict__ wfrag) {
    int t = blockIdx.x * 256 + threadIdx.x;
    if (t >= 3 * 32 * 2 * 64) return;
    int lane = t & 63, kf = (t >> 6) & 1, nf = (t >> 7) & 31, z = t >> 12;
    const float* W = (z == 0) ? Wq : (z == 1) ? Wk : Wvu;
    int col = nf * 16 + (lane & 15);
    int krow = kf * 32 + (lane >> 4) * 8;
    uint4 r;
    uint32_t v[8];
    #pragma unroll
    for (int j = 0; j < 8; ++j) v[j] = f2bf(W[(size_t)(krow + j) * NH + col]);
    r.x = v[0] | (v[1] << 16); r.y = v[2] | (v[3] << 16);
    r.z = v[4] | (v[5] << 16); r.w = v[6] | (v[7] << 16);
    *(uint4*)(wfrag + (size_t)t * 8) = r;
}

// ---- MFMA projection: out_z = xb @ W_z, bf16, no LDS ----
__global__ __launch_bounds__(256) void k_proj(const ushort* __restrict__ xb,
        const ushort* __restrict__ wfrag,
        __hip_bfloat16* __restrict__ q, __hip_bfloat16* __restrict__ kk,
        __hip_bfloat16* __restrict__ vu) {
    int z = blockIdx.y;
    __hip_bfloat16* outp = (z == 0) ? q : (z == 1) ? kk : vu;
    int row0 = blockIdx.x * 64;
    int wv = threadIdx.x >> 6, lane = threadIdx.x & 63;
    int arow = lane & 15, akoff = (lane >> 4) * 8;

    bf16x8 a[4][2];
    #pragma unroll
    for (int mf = 0; mf < 4; ++mf)
        #pragma unroll
        for (int kf = 0; kf < 2; ++kf)
            a[mf][kf] = *(const bf16x8*)(xb + (size_t)(row0 + mf * 16 + arow) * 64 + kf * 32 + akoff);

    #pragma unroll
    for (int nf = 0; nf < 8; ++nf) {
        size_t base = ((size_t)((z * 32 + wv * 8 + nf) * 2) * 64 + lane) * 8;
        bf16x8 b0 = *(const bf16x8*)(wfrag + base);
        bf16x8 b1 = *(const bf16x8*)(wfrag + base + 64 * 8);
        int col = wv * 128 + nf * 16 + (lane & 15);
        #pragma unroll
        for (int mf = 0; mf < 4; ++mf) {
            f32x4 acc = {0.f, 0.f, 0.f, 0.f};
            acc = __builtin_amdgcn_mfma_f32_16x16x32_bf16(a[mf][0], b0, acc, 0, 0, 0);
            acc = __builtin_amdgcn_mfma_f32_16x16x32_bf16(a[mf][1], b1, acc, 0, 0, 0);
            int rbase = row0 + mf * 16 + (lane >> 4) * 4;
            #pragma unroll
            for (int rg = 0; rg < 4; ++rg)
                outp[(size_t)(rbase + rg) * NH + col] = __float2bfloat16(acc[rg]);
        }
    }
}

// ---- build sparse index tuples (flipped: row >= col) + hash insert ----
__global__ void k_build_idx(const int* __restrict__ g_ints, const int* __restrict__ l_offs,
                            const float* __restrict__ meansf,
                            int* __restrict__ idxrow, int* __restrict__ idxcol,
                            int* __restrict__ hkey, int* __restrict__ hval) {
    int b = blockIdx.x;
    int* keys = hkey + b * HSZ;
    int* vals = hval + b * HSZ;
    for (int s = threadIdx.x; s < VS; s += blockDim.x) {
        int k = s / 20, slot = s % 20;
        float m0 = meansf[2 * k], m1 = meansf[2 * k + 1];
        int i0, i1;
        if (slot < 4) {
            float a  = (slot & 2) ? ceilf(m0) : floorf(m0);
            float bb = (slot & 1) ? ceilf(m1) : floorf(m1);
            a  = fminf(fmaxf(a, 0.f), (float)(T - 1));
            bb = fminf(fmaxf(bb, 0.f), (float)(T - 1));
            i0 = (int)a; i1 = (int)bb;
        } else if (slot < 12) {
            const int* p = g_ints + ((size_t)((b * KP + k) * GADD) + (slot - 4)) * 2;
            i0 = p[0]; i1 = p[1];
        } else {
            int lo0 = (int)fminf(fmaxf(floorf(m0) - (float)(REGION / 2), 0.f), (float)(T - REGION));
            int lo1 = (int)fminf(fmaxf(floorf(m1) - (float)(REGION / 2), 0.f), (float)(T - REGION));
            const int* p = l_offs + ((size_t)((b * KP + k) * RADD) + (slot - 12)) * 2;
            i0 = lo0 + p[0]; i1 = lo1 + p[1];
        }
        int row = max(i0, i1), col = min(i0, i1);
        idxrow[b * VS + s] = row;
        idxcol[b * VS + s] = col;
        // hash insert: min original index per id (deterministic)
        int id = row * T + col;
        unsigned h = ((unsigned)id * 2654435761u) >> 18;   // -> [0, 16384)
        while (true) {
            int old = atomicCAS(&keys[h], -1, id);
            if (old == -1 || old == id) { atomicMin(&vals[h], s); break; }
            h = (h + 1) & (HSZ - 1);
        }
    }
}

// ---- per-chunk local rank (shuffles) + chunk histogram + dup lookup ----
// one wave per 256-entry chunk; lane handles s = chunk*256 + i*64 + lane, i=0..3
__global__ __launch_bounds__(256) void k_local(const int* __restrict__ idxrow,
        const int* __restrict__ idxcol, const int* __restrict__ hkey,
        const int* __restrict__ hval, int* __restrict__ lrank, int* __restrict__ dup,
        int* __restrict__ chist) {
    int b = blockIdx.y;
    int wv = threadIdx.x >> 6, lane = threadIdx.x & 63;
    int chunk = blockIdx.x * 4 + wv;
    int s0 = chunk * 256 + lane;
    int r0 = idxrow[b * VS + s0];
    int r1 = idxrow[b * VS + s0 + 64];
    int r2 = idxrow[b * VS + s0 + 128];
    int r3 = idxrow[b * VS + s0 + 192];
    int lr0 = 0, lr1 = 0, lr2 = 0, lr3 = 0;
    #pragma unroll
    for (int j = 0; j < 64; ++j) {
        int a0 = __shfl(r0, j), a1 = __shfl(r1, j), a2 = __shfl(r2, j), a3 = __shfl(r3, j);
        bool lt = (j < lane);
        lr0 += (lt && a0 == r0);
        lr1 += (a0 == r1) + (lt && a1 == r1);
        lr2 += (a0 == r2) + (a1 == r2) + (lt && a2 == r2);
        lr3 += (a0 == r3) + (a1 == r3) + (a2 == r3) + (lt && a3 == r3);
    }
    lrank[b * VS + s0]       = lr0;
    lrank[b * VS + s0 + 64]  = lr1;
    lrank[b * VS + s0 + 128] = lr2;
    lrank[b * VS + s0 + 192] = lr3;
    atomicAdd(&chist[(size_t)(b * T + r0) * NCHUNK + chunk], 1);
    atomicAdd(&chist[(size_t)(b * T + r1) * NCHUNK + chunk], 1);
    atomicAdd(&chist[(size_t)(b * T + r2) * NCHUNK + chunk], 1);
    atomicAdd(&chist[(size_t)(b * T + r3) * NCHUNK + chunk], 1);
    // dup lookups
    const int* keys = hkey + b * HSZ;
    const int* vals = hval + b * HSZ;
    #pragma unroll
    for (int i = 0; i < 4; ++i) {
        int s = s0 + i * 64;
        int id = idxrow[b * VS + s] * T + idxcol[b * VS + s];
        unsigned h = ((unsigned)id * 2654435761u) >> 18;
        while (keys[h] != id) h = (h + 1) & (HSZ - 1);
        dup[b * VS + s] = (vals[h] != s);
    }
}

// ---- per-(b,row): exclusive prefix over chunks, total -> rowcnt ----
__global__ void k_chunkscan(int* __restrict__ chist, int* __restrict__ rowcnt) {
    int idx = blockIdx.x * 256 + threadIdx.x;   // b*T + row
    int* p = chist + (size_t)idx * NCHUNK;
    int acc = 0;
    #pragma unroll
    for (int c = 0; c < NCHUNK; ++c) { int v = p[c]; p[c] = acc; acc += v; }
    rowcnt[idx] = acc;
}

// ---- column sums of the (non-dup) density matrix ----
__global__ void k_colsum(const int* __restrict__ idxrow, const int* __restrict__ idxcol,
                         const int* __restrict__ dup, const float* __restrict__ meansf,
                         const float* __restrict__ sigt, float* __restrict__ colsum) {
    int k = blockIdx.x, b = blockIdx.y;
    float m0 = meansf[2 * k], m1 = meansf[2 * k + 1];
    float inv = 1.f / sigt[k];
    float acc = 0.f;
    for (int s = threadIdx.x; s < VS; s += 256) {
        if (!dup[b * VS + s]) {
            float d0 = ((float)idxrow[b * VS + s] - m0) * inv;
            float d1 = ((float)idxcol[b * VS + s] - m1) * inv;
            acc += __expf(-0.5f * (d0 * d0 + d1 * d1));
        }
    }
    __shared__ float red[256];
    red[threadIdx.x] = acc;
    __syncthreads();
    for (int o = 128; o > 0; o >>= 1) {
        if (threadIdx.x < o) red[threadIdx.x] += red[threadIdx.x + o];
        __syncthreads();
    }
    if (threadIdx.x == 0) colsum[b * KP + k] = red[0];
}

// ---- per-entry weight = sum_k prop/colsum_k ----
__global__ void k_weights(const int* __restrict__ idxrow, const int* __restrict__ idxcol,
                          const int* __restrict__ dup, const float* __restrict__ meansf,
                          const float* __restrict__ sigt, const float* __restrict__ colsum,
                          float* __restrict__ wts) {
    int b = blockIdx.y;
    int s = blockIdx.x * 256 + threadIdx.x;
    __shared__ float sm[2 * KP], ss[KP], rc[KP];
    for (int k = threadIdx.x; k < KP; k += 256) {
        sm[2 * k] = meansf[2 * k];
        sm[2 * k + 1] = meansf[2 * k + 1];
        ss[k] = 1.f / sigt[k];
        rc[k] = 1.f / colsum[b * KP + k];
    }
    __syncthreads();
    float w = 0.f;
    if (!dup[b * VS + s]) {
        float r = (float)idxrow[b * VS + s], c = (float)idxcol[b * VS + s];
        #pragma unroll 4
        for (int k = 0; k < KP; ++k) {
            float d0 = (r - sm[2 * k]) * ss[k];
            float d1 = (c - sm[2 * k + 1]) * ss[k];
            w += __expf(-0.5f * (d0 * d0 + d1 * d1)) * rc[k];
        }
    }
    wts[b * VS + s] = w;
}

// ---- exclusive prefix sum per batch (4096 rows) ----
__global__ __launch_bounds__(1024) void k_scan(const int* __restrict__ rowcnt, int* __restrict__ rowptr) {
    int b = blockIdx.x, tid = threadIdx.x;
    __shared__ int part[1024];
    int v[4]; int loc = 0;
    for (int j = 0; j < 4; ++j) { v[j] = rowcnt[b * T + tid * 4 + j]; loc += v[j]; }
    part[tid] = loc;
    __syncthreads();
    for (int off = 1; off < 1024; off <<= 1) {
        int t = (tid >= off) ? part[tid - off] : 0;
        __syncthreads();
        part[tid] += t;
        __syncthreads();
    }
    int excl = part[tid] - loc;
    for (int j = 0; j < 4; ++j) { rowptr[b * (T + 1) + tid * 4 + j] = excl; excl += v[j]; }
    if (tid == 1023) rowptr[b * (T + 1) + T] = part[1023];
}

// ---- deterministic counting-sort scatter ----
__global__ void k_scatter(const int* __restrict__ idxrow, const int* __restrict__ idxcol,
                          const float* __restrict__ wts, const int* __restrict__ lrank,
                          const int* __restrict__ chist, const int* __restrict__ rowptr,
                          int* __restrict__ scol, float* __restrict__ sw) {
    int b = blockIdx.y;
    int s = blockIdx.x * 256 + threadIdx.x;
    int r = idxrow[b * VS + s];
    int pos = rowptr[b * (T + 1) + r] + chist[(size_t)(b * T + r) * NCHUNK + (s >> 8)]
            + lrank[b * VS + s];
    scol[b * VS + pos] = idxcol[b * VS + s];
    sw[b * VS + pos] = wts[b * VS + s];
}

// ---- attention: one wave per row, lane = head*8 + li, 8 feats/lane ----
__global__ __launch_bounds__(256) void k_attn(
        const __hip_bfloat16* __restrict__ q, const __hip_bfloat16* __restrict__ kk,
        const __hip_bfloat16* __restrict__ vu, const int* __restrict__ rowptr,
        const int* __restrict__ scol, const float* __restrict__ sw,
        const float* __restrict__ bu, float* __restrict__ out) {
    int gr = blockIdx.x * 4 + (threadIdx.x >> 6);   // b*T + r
    int b = gr >> 12;
    int r = gr & (T - 1);
    int lane = threadIdx.x & 63;
    int p0 = rowptr[b * (T + 1) + r], p1 = rowptr[b * (T + 1) + r + 1];

    uint4 q4 = *(const uint4*)((const ushort*)q + (size_t)gr * NH + lane * 8);
    float qv[8] = { bflo(q4.x), bfhi(q4.x), bflo(q4.y), bfhi(q4.y),
                    bflo(q4.z), bfhi(q4.z), bflo(q4.w), bfhi(q4.w) };

    float m = -INFINITY, ssum = 0.f;
    float av[8] = {0.f,0.f,0.f,0.f,0.f,0.f,0.f,0.f};

    for (int e = p0; e < p1; ++e) {
        int c = scol[b * VS + e];
        float w = sw[b * VS + e];
        size_t off = ((size_t)(b * T + c)) * NH + lane * 8;
        uint4 k4 = *(const uint4*)((const ushort*)kk + off);
        float dp = qv[0]*bflo(k4.x) + qv[1]*bfhi(k4.x) + qv[2]*bflo(k4.y) + qv[3]*bfhi(k4.y)
                 + qv[4]*bflo(k4.z) + qv[5]*bfhi(k4.z) + qv[6]*bflo(k4.w) + qv[7]*bfhi(k4.w);
        dp += __shfl_xor(dp, 1);
        dp += __shfl_xor(dp, 2);
        dp += __shfl_xor(dp, 4);
        float d = 0.125f * w * dp;                 // (e^-0.25)^2 = 1/8
        float nm = fmaxf(m, d);
        float corr = __expf(m - nm);
        float t = __expf(d - nm);
        uint4 v4 = *(const uint4*)((const ushort*)vu + off);
        float vf[8] = { bflo(v4.x), bfhi(v4.x), bflo(v4.y), bfhi(v4.y),
                        bflo(v4.z), bfhi(v4.z), bflo(v4.w), bfhi(v4.w) };
        ssum = ssum * corr + t;
        #pragma unroll
        for (int u = 0; u < 8; ++u) av[u] = av[u] * corr + t * vf[u];
        m = nm;
    }

    float inv = (p1 > p0) ? (1.f / ssum) : 0.f;
    float res[8];
    #pragma unroll
    for (int u = 0; u < 8; ++u) {
        float v = av[u] * inv;
        v += __shfl_xor(v, 8);
        v += __shfl_xor(v, 16);
        v += __shfl_xor(v, 32);
        res[u] = v;
    }
    if (lane < 8) {
        float4 o0 = make_float4(res[0] + bu[lane*8+0], res[1] + bu[lane*8+1],
                                res[2] + bu[lane*8+2], res[3] + bu[lane*8+3]);
        float4 o1 = make_float4(res[4] + bu[lane*8+4], res[5] + bu[lane*8+5],
                                res[6] + bu[lane*8+6], res[7] + bu[lane*8+7]);
        *(float4*)(out + (size_t)gr * E + lane * 8)     = o0;
        *(float4*)(out + (size_t)gr * E + lane * 8 + 4) = o1;
    }
}

extern "C" void kernel_launch(void* const* d_in, const int* in_sizes, int n_in,
                              void* d_out, int out_size, void* d_ws, size_t ws_size,
                              hipStream_t stream) {
    const float* x        = (const float*)d_in[0];
    const float* Wq       = (const float*)d_in[1];
    const float* Wk       = (const float*)d_in[2];
    const float* Wv       = (const float*)d_in[3];
    const float* Wu       = (const float*)d_in[4];
    const float* bu       = (const float*)d_in[5];
    const float* means_p  = (const float*)d_in[6];
    const float* sigmas_p = (const float*)d_in[7];
    const int*   g_ints   = (const int*)d_in[8];
    const int*   l_offs   = (const int*)d_in[9];
    float* out = (float*)d_out;

    char* ws = (char*)d_ws;
    size_t o = 0;
    auto alloc = [&](size_t bytes) -> void* {
        void* p = ws + o;
        o += (bytes + 255) & ~(size_t)255;
        return p;
    };
    __hip_bfloat16* q   = (__hip_bfloat16*)alloc((size_t)B * T * NH * 2);
    __hip_bfloat16* kk  = (__hip_bfloat16*)alloc((size_t)B * T * NH * 2);
    __hip_bfloat16* vu  = (__hip_bfloat16*)alloc((size_t)B * T * NH * 2);
    ushort* xb    = (ushort*)alloc((size_t)B * T * E * 2);
    ushort* wfrag = (ushort*)alloc((size_t)3 * 32 * 2 * 64 * 8 * 2);
    float* Wvu    = (float*)alloc((size_t)E * NH * 4);
    float* meansf = (float*)alloc(KP * 2 * 4);
    float* sigt   = (float*)alloc(KP * 4);
    int*   idxrow = (int*)alloc((size_t)B * VS * 4);
    int*   idxcol = (int*)alloc((size_t)B * VS * 4);
    float* wts    = (float*)alloc((size_t)B * VS * 4);
    int*   lrank  = (int*)alloc((size_t)B * VS * 4);
    int*   dup    = (int*)alloc((size_t)B * VS * 4);
    float* colsum = (float*)alloc((size_t)B * KP * 4);
    int*   rowcnt = (int*)alloc((size_t)B * T * 4);
    int*   rowptr = (int*)alloc((size_t)B * (T + 1) * 4);
    int*   scol   = (int*)alloc((size_t)B * VS * 4);
    float* sw     = (float*)alloc((size_t)B * VS * 4);
    int*   hkey   = (int*)alloc((size_t)B * HSZ * 4);
    int*   hval   = (int*)alloc((size_t)B * HSZ * 4);
    int*   chist  = (int*)alloc((size_t)B * T * NCHUNK * 4);

    hipMemsetAsync(hkey, 0xFF, (size_t)B * HSZ * 4, stream);       // keys = -1
    hipMemsetAsync(hval, 0x7F, (size_t)B * HSZ * 4, stream);       // vals = big
    hipMemsetAsync(chist, 0, (size_t)B * T * NCHUNK * 4, stream);

    k_points<<<1, 256, 0, stream>>>(means_p, sigmas_p, meansf, sigt);
    k_wvu<<<(E * NH + 255) / 256, 256, 0, stream>>>(Wv, Wu, Wvu);
    k_prep_x<<<(B * T * E / 8) / 256, 256, 0, stream>>>(x, xb);
    k_prep_w<<<(3 * 32 * 2 * 64 + 255) / 256, 256, 0, stream>>>(Wq, Wk, Wvu, wfrag);
    k_build_idx<<<B, 256, 0, stream>>>(g_ints, l_offs, meansf, idxrow, idxcol, hkey, hval);
    k_local<<<dim3(VS / 1024, B), 256, 0, stream>>>(idxrow, idxcol, hkey, hval, lrank, dup, chist);
    k_chunkscan<<<B * T / 256, 256, 0, stream>>>(chist, rowcnt);
    k_colsum<<<dim3(KP, B), 256, 0, stream>>>(idxrow, idxcol, dup, meansf, sigt, colsum);
    k_weights<<<dim3(VS / 256, B), 256, 0, stream>>>(idxrow, idxcol, dup, meansf, sigt, colsum, wts);
    k_scan<<<B, 1024, 0, stream>>>(rowcnt, rowptr);
    k_scatter<<<dim3(VS / 256, B), 256, 0, stream>>>(idxrow, idxcol, wts, lrank, chist, rowptr, scol, sw);
    k_proj<<<dim3(B * T / 64, 3), 256, 0, stream>>>(xb, wfrag, q, kk, vu);
    k_attn<<<B * T / 4, 256, 0, stream>>>(q, kk, vu, rowptr, scol, sw, bu, out);
}

// Round 4
// 229.346 us; speedup vs baseline: 2.0545x; 1.1756x over previous
//
#include <hip/hip_runtime.h>
#include <hip/hip_bf16.h>
#include <math.h>

#define B 16
#define T 4096
#define E 64
#define H 8
#define KP 256
#define GADD 8
#define RADD 8
#define REGION 64
#define VS (KP * (4 + GADD + RADD))   // 5120
#define NH (H * E)                    // 512
#define NCHUNK 20                     // VS / 256
#define HSZ 16384                     // hash slots per batch

typedef __attribute__((ext_vector_type(8))) short bf16x8;
typedef __attribute__((ext_vector_type(4))) float f32x4;

__device__ inline ushort f2bf(float f) {
    union { __hip_bfloat16 h; ushort u; } cv;
    cv.h = __float2bfloat16(f);
    return cv.u;
}
__device__ inline float bflo(uint32_t p) { return __uint_as_float(p << 16); }
__device__ inline float bfhi(uint32_t p) { return __uint_as_float(p & 0xffff0000u); }

// ---- K points: flip -> sigmoid*(t-1) means; softplus sigmas ----
__global__ void k_points(const float* __restrict__ means_p, const float* __restrict__ sigmas_p,
                         float* __restrict__ meansf, float* __restrict__ sigt) {
    int k = threadIdx.x;
    if (k >= KP) return;
    float a = means_p[2 * k], b = means_p[2 * k + 1];
    float hi = fmaxf(a, b), lo = fminf(a, b);
    meansf[2 * k]     = (1.f / (1.f + expf(-hi))) * (float)(T - 1);
    meansf[2 * k + 1] = (1.f / (1.f + expf(-lo))) * (float)(T - 1);
    float sp = sigmas_p[k] + 2.0f;
    float s = (sp > 20.f) ? sp : log1pf(expf(sp));
    sigt[k] = (s + 0.05f) * (float)T;
}

// ---- Wvu_h = Wv_h @ Wu_h  (fold output projection into V) ----
__global__ void k_wvu(const float* __restrict__ Wv, const float* __restrict__ Wu,
                      float* __restrict__ Wvu) {
    int idx = blockIdx.x * blockDim.x + threadIdx.x;
    if (idx >= E * NH) return;
    int i = idx / NH, c = idx % NH;
    int h = c / E, j = c % E;
    float acc = 0.f;
    for (int d = 0; d < E; ++d)
        acc += Wv[i * NH + h * E + d] * Wu[(h * E + d) * E + j];
    Wvu[i * NH + c] = acc;
}

// ---- x f32 -> bf16 ----
__global__ void k_prep_x(const float* __restrict__ x, ushort* __restrict__ xb) {
    int i = (blockIdx.x * 256 + threadIdx.x) * 8;
    float4 a = *(const float4*)(x + i);
    float4 b = *(const float4*)(x + i + 4);
    uint4 r;
    r.x = (uint32_t)f2bf(a.x) | ((uint32_t)f2bf(a.y) << 16);
    r.y = (uint32_t)f2bf(a.z) | ((uint32_t)f2bf(a.w) << 16);
    r.z = (uint32_t)f2bf(b.x) | ((uint32_t)f2bf(b.y) << 16);
    r.w = (uint32_t)f2bf(b.z) | ((uint32_t)f2bf(b.w) << 16);
    *(uint4*)(xb + i) = r;
}

// ---- pre-pack W into MFMA B-fragment lane order (bf16) ----
__global__ void k_prep_w(const float* __restrict__ Wq, const float* __restrict__ Wk,
                         const float* __restrict__ Wvu, ushort* __restrict__ wfrag) {
    int t = blockIdx.x * 256 + threadIdx.x;
    if (t >= 3 * 32 * 2 * 64) return;
    int lane = t & 63, kf = (t >> 6) & 1, nf = (t >> 7) & 31, z = t >> 12;
    const float* W = (z == 0) ? Wq : (z == 1) ? Wk : Wvu;
    int col = nf * 16 + (lane & 15);
    int krow = kf * 32 + (lane >> 4) * 8;
    uint4 r;
    uint32_t v[8];
    #pragma unroll
    for (int j = 0; j < 8; ++j) v[j] = f2bf(W[(size_t)(krow + j) * NH + col]);
    r.x = v[0] | (v[1] << 16); r.y = v[2] | (v[3] << 16);
    r.z = v[4] | (v[5] << 16); r.w = v[6] | (v[7] << 16);
    *(uint4*)(wfrag + (size_t)t * 8) = r;
}

// ---- MFMA projection: out_z = xb @ W_z, bf16, no LDS, coalesced 16B stores ----
// Output layout is PERMUTED within each 128-col block:
//   stored position p = wv*128 + (lane&15)*8 + nf  <->  orig col = wv*128 + nf*16 + (lane&15)
// k_attn decodes this (lane holds 4 feats of head 2*blk and 4 of head 2*blk+1).
__global__ __launch_bounds__(256) void k_proj(const ushort* __restrict__ xb,
        const ushort* __restrict__ wfrag,
        __hip_bfloat16* __restrict__ q, __hip_bfloat16* __restrict__ kk,
        __hip_bfloat16* __restrict__ vu) {
    int z = blockIdx.y;
    __hip_bfloat16* outp = (z == 0) ? q : (z == 1) ? kk : vu;
    int row0 = blockIdx.x * 64;
    int wv = threadIdx.x >> 6, lane = threadIdx.x & 63;
    int arow = lane & 15, akoff = (lane >> 4) * 8;

    bf16x8 bfr[8][2];
    #pragma unroll
    for (int nf = 0; nf < 8; ++nf) {
        size_t base = ((size_t)((z * 32 + wv * 8 + nf) * 2) * 64 + lane) * 8;
        bfr[nf][0] = *(const bf16x8*)(wfrag + base);
        bfr[nf][1] = *(const bf16x8*)(wfrag + base + 64 * 8);
    }

    #pragma unroll
    for (int mf = 0; mf < 4; ++mf) {
        bf16x8 a0 = *(const bf16x8*)(xb + (size_t)(row0 + mf * 16 + arow) * 64 + akoff);
        bf16x8 a1 = *(const bf16x8*)(xb + (size_t)(row0 + mf * 16 + arow) * 64 + 32 + akoff);
        f32x4 acc[8];
        #pragma unroll
        for (int nf = 0; nf < 8; ++nf) {
            f32x4 t = {0.f, 0.f, 0.f, 0.f};
            t = __builtin_amdgcn_mfma_f32_16x16x32_bf16(a0, bfr[nf][0], t, 0, 0, 0);
            t = __builtin_amdgcn_mfma_f32_16x16x32_bf16(a1, bfr[nf][1], t, 0, 0, 0);
            acc[nf] = t;
        }
        int rbase = row0 + mf * 16 + (lane >> 4) * 4;
        #pragma unroll
        for (int rg = 0; rg < 4; ++rg) {
            uint4 o;
            o.x = (uint32_t)f2bf(acc[0][rg]) | ((uint32_t)f2bf(acc[1][rg]) << 16);
            o.y = (uint32_t)f2bf(acc[2][rg]) | ((uint32_t)f2bf(acc[3][rg]) << 16);
            o.z = (uint32_t)f2bf(acc[4][rg]) | ((uint32_t)f2bf(acc[5][rg]) << 16);
            o.w = (uint32_t)f2bf(acc[6][rg]) | ((uint32_t)f2bf(acc[7][rg]) << 16);
            *(uint4*)((ushort*)outp + (size_t)(rbase + rg) * NH + wv * 128 + (lane & 15) * 8) = o;
        }
    }
}

// ---- build sparse index tuples (flipped: row >= col) + hash insert ----
__global__ void k_build_idx(const int* __restrict__ g_ints, const int* __restrict__ l_offs,
                            const float* __restrict__ meansf,
                            int* __restrict__ idxrow, int* __restrict__ idxcol,
                            int* __restrict__ hkey, int* __restrict__ hval) {
    int b = blockIdx.x;
    int* keys = hkey + b * HSZ;
    int* vals = hval + b * HSZ;
    for (int s = threadIdx.x; s < VS; s += blockDim.x) {
        int k = s / 20, slot = s % 20;
        float m0 = meansf[2 * k], m1 = meansf[2 * k + 1];
        int i0, i1;
        if (slot < 4) {
            float a  = (slot & 2) ? ceilf(m0) : floorf(m0);
            float bb = (slot & 1) ? ceilf(m1) : floorf(m1);
            a  = fminf(fmaxf(a, 0.f), (float)(T - 1));
            bb = fminf(fmaxf(bb, 0.f), (float)(T - 1));
            i0 = (int)a; i1 = (int)bb;
        } else if (slot < 12) {
            const int* p = g_ints + ((size_t)((b * KP + k) * GADD) + (slot - 4)) * 2;
            i0 = p[0]; i1 = p[1];
        } else {
            int lo0 = (int)fminf(fmaxf(floorf(m0) - (float)(REGION / 2), 0.f), (float)(T - REGION));
            int lo1 = (int)fminf(fmaxf(floorf(m1) - (float)(REGION / 2), 0.f), (float)(T - REGION));
            const int* p = l_offs + ((size_t)((b * KP + k) * RADD) + (slot - 12)) * 2;
            i0 = lo0 + p[0]; i1 = lo1 + p[1];
        }
        int row = max(i0, i1), col = min(i0, i1);
        idxrow[b * VS + s] = row;
        idxcol[b * VS + s] = col;
        int id = row * T + col;
        unsigned h = ((unsigned)id * 2654435761u) >> 18;
        while (true) {
            int old = atomicCAS(&keys[h], -1, id);
            if (old == -1 || old == id) { atomicMin(&vals[h], s); break; }
            h = (h + 1) & (HSZ - 1);
        }
    }
}

// ---- per-chunk local rank (shuffles) + chunk histogram + dup lookup ----
__global__ __launch_bounds__(256) void k_local(const int* __restrict__ idxrow,
        const int* __restrict__ idxcol, const int* __restrict__ hkey,
        const int* __restrict__ hval, int* __restrict__ lrank, int* __restrict__ dup,
        int* __restrict__ chist) {
    int b = blockIdx.y;
    int wv = threadIdx.x >> 6, lane = threadIdx.x & 63;
    int chunk = blockIdx.x * 4 + wv;
    int s0 = chunk * 256 + lane;
    int r0 = idxrow[b * VS + s0];
    int r1 = idxrow[b * VS + s0 + 64];
    int r2 = idxrow[b * VS + s0 + 128];
    int r3 = idxrow[b * VS + s0 + 192];
    int lr0 = 0, lr1 = 0, lr2 = 0, lr3 = 0;
    #pragma unroll
    for (int j = 0; j < 64; ++j) {
        int a0 = __shfl(r0, j), a1 = __shfl(r1, j), a2 = __shfl(r2, j), a3 = __shfl(r3, j);
        bool lt = (j < lane);
        lr0 += (lt && a0 == r0);
        lr1 += (a0 == r1) + (lt && a1 == r1);
        lr2 += (a0 == r2) + (a1 == r2) + (lt && a2 == r2);
        lr3 += (a0 == r3) + (a1 == r3) + (a2 == r3) + (lt && a3 == r3);
    }
    lrank[b * VS + s0]       = lr0;
    lrank[b * VS + s0 + 64]  = lr1;
    lrank[b * VS + s0 + 128] = lr2;
    lrank[b * VS + s0 + 192] = lr3;
    atomicAdd(&chist[(size_t)(b * T + r0) * NCHUNK + chunk], 1);
    atomicAdd(&chist[(size_t)(b * T + r1) * NCHUNK + chunk], 1);
    atomicAdd(&chist[(size_t)(b * T + r2) * NCHUNK + chunk], 1);
    atomicAdd(&chist[(size_t)(b * T + r3) * NCHUNK + chunk], 1);
    const int* keys = hkey + b * HSZ;
    const int* vals = hval + b * HSZ;
    #pragma unroll
    for (int i = 0; i < 4; ++i) {
        int s = s0 + i * 64;
        int id = idxrow[b * VS + s] * T + idxcol[b * VS + s];
        unsigned h = ((unsigned)id * 2654435761u) >> 18;
        while (keys[h] != id) h = (h + 1) & (HSZ - 1);
        dup[b * VS + s] = (vals[h] != s);
    }
}

// ---- per-(b,row): exclusive prefix over chunks, total -> rowcnt ----
__global__ void k_chunkscan(int* __restrict__ chist, int* __restrict__ rowcnt) {
    int idx = blockIdx.x * 256 + threadIdx.x;   // b*T + row
    int* p = chist + (size_t)idx * NCHUNK;
    int acc = 0;
    #pragma unroll
    for (int c = 0; c < NCHUNK; ++c) { int v = p[c]; p[c] = acc; acc += v; }
    rowcnt[idx] = acc;
}

// ---- column sums of the (non-dup) density matrix ----
__global__ void k_colsum(const int* __restrict__ idxrow, const int* __restrict__ idxcol,
                         const int* __restrict__ dup, const float* __restrict__ meansf,
                         const float* __restrict__ sigt, float* __restrict__ colsum) {
    int k = blockIdx.x, b = blockIdx.y;
    float m0 = meansf[2 * k], m1 = meansf[2 * k + 1];
    float inv = 1.f / sigt[k];
    float acc = 0.f;
    for (int s = threadIdx.x; s < VS; s += 256) {
        if (!dup[b * VS + s]) {
            float d0 = ((float)idxrow[b * VS + s] - m0) * inv;
            float d1 = ((float)idxcol[b * VS + s] - m1) * inv;
            acc += __expf(-0.5f * (d0 * d0 + d1 * d1));
        }
    }
    __shared__ float red[256];
    red[threadIdx.x] = acc;
    __syncthreads();
    for (int o = 128; o > 0; o >>= 1) {
        if (threadIdx.x < o) red[threadIdx.x] += red[threadIdx.x + o];
        __syncthreads();
    }
    if (threadIdx.x == 0) colsum[b * KP + k] = red[0];
}

// ---- per-entry weight = sum_k prop/colsum_k ----
__global__ void k_weights(const int* __restrict__ idxrow, const int* __restrict__ idxcol,
                          const int* __restrict__ dup, const float* __restrict__ meansf,
                          const float* __restrict__ sigt, const float* __restrict__ colsum,
                          float* __restrict__ wts) {
    int b = blockIdx.y;
    int s = blockIdx.x * 256 + threadIdx.x;
    __shared__ float sm[2 * KP], ss[KP], rc[KP];
    for (int k = threadIdx.x; k < KP; k += 256) {
        sm[2 * k] = meansf[2 * k];
        sm[2 * k + 1] = meansf[2 * k + 1];
        ss[k] = 1.f / sigt[k];
        rc[k] = 1.f / colsum[b * KP + k];
    }
    __syncthreads();
    float w = 0.f;
    if (!dup[b * VS + s]) {
        float r = (float)idxrow[b * VS + s], c = (float)idxcol[b * VS + s];
        #pragma unroll 4
        for (int k = 0; k < KP; ++k) {
            float d0 = (r - sm[2 * k]) * ss[k];
            float d1 = (c - sm[2 * k + 1]) * ss[k];
            w += __expf(-0.5f * (d0 * d0 + d1 * d1)) * rc[k];
        }
    }
    wts[b * VS + s] = w;
}

// ---- exclusive prefix sum per batch (4096 rows) ----
__global__ __launch_bounds__(1024) void k_scan(const int* __restrict__ rowcnt, int* __restrict__ rowptr) {
    int b = blockIdx.x, tid = threadIdx.x;
    __shared__ int part[1024];
    int v[4]; int loc = 0;
    for (int j = 0; j < 4; ++j) { v[j] = rowcnt[b * T + tid * 4 + j]; loc += v[j]; }
    part[tid] = loc;
    __syncthreads();
    for (int off = 1; off < 1024; off <<= 1) {
        int t = (tid >= off) ? part[tid - off] : 0;
        __syncthreads();
        part[tid] += t;
        __syncthreads();
    }
    int excl = part[tid] - loc;
    for (int j = 0; j < 4; ++j) { rowptr[b * (T + 1) + tid * 4 + j] = excl; excl += v[j]; }
    if (tid == 1023) rowptr[b * (T + 1) + T] = part[1023];
}

// ---- deterministic counting-sort scatter ----
__global__ void k_scatter(const int* __restrict__ idxrow, const int* __restrict__ idxcol,
                          const float* __restrict__ wts, const int* __restrict__ lrank,
                          const int* __restrict__ chist, const int* __restrict__ rowptr,
                          int* __restrict__ scol, float* __restrict__ sw) {
    int b = blockIdx.y;
    int s = blockIdx.x * 256 + threadIdx.x;
    int r = idxrow[b * VS + s];
    int pos = rowptr[b * (T + 1) + r] + chist[(size_t)(b * T + r) * NCHUNK + (s >> 8)]
            + lrank[b * VS + s];
    scol[b * VS + pos] = idxcol[b * VS + s];
    sw[b * VS + pos] = wts[b * VS + s];
}

// ---- attention over permuted layout: wave per row; 16-lane group blk handles
// heads 2*blk (regs 0-3) and 2*blk+1 (regs 4-7); feature j = (u%4)*16 + (lane&15) ----
__global__ __launch_bounds__(256) void k_attn(
        const __hip_bfloat16* __restrict__ q, const __hip_bfloat16* __restrict__ kk,
        const __hip_bfloat16* __restrict__ vu, const int* __restrict__ rowptr,
        const int* __restrict__ scol, const float* __restrict__ sw,
        const float* __restrict__ bu, float* __restrict__ out) {
    int gr = blockIdx.x * 4 + (threadIdx.x >> 6);   // b*T + r
    int b = gr >> 12;
    int r = gr & (T - 1);
    int lane = threadIdx.x & 63;
    int p0 = rowptr[b * (T + 1) + r], p1 = rowptr[b * (T + 1) + r + 1];

    uint4 q4 = *(const uint4*)((const ushort*)q + (size_t)gr * NH + lane * 8);
    float qv[8] = { bflo(q4.x), bfhi(q4.x), bflo(q4.y), bfhi(q4.y),
                    bflo(q4.z), bfhi(q4.z), bflo(q4.w), bfhi(q4.w) };

    float m0 = -INFINITY, s0 = 0.f, m1 = -INFINITY, s1 = 0.f;
    float av[8] = {0.f,0.f,0.f,0.f,0.f,0.f,0.f,0.f};

    for (int e = p0; e < p1; ++e) {
        int c = scol[b * VS + e];
        float w = sw[b * VS + e];
        size_t off = ((size_t)(b * T + c)) * NH + lane * 8;
        uint4 k4 = *(const uint4*)((const ushort*)kk + off);
        float dp0 = qv[0]*bflo(k4.x) + qv[1]*bfhi(k4.x) + qv[2]*bflo(k4.y) + qv[3]*bfhi(k4.y);
        float dp1 = qv[4]*bflo(k4.z) + qv[5]*bfhi(k4.z) + qv[6]*bflo(k4.w) + qv[7]*bfhi(k4.w);
        dp0 += __shfl_xor(dp0, 1);
        dp0 += __shfl_xor(dp0, 2);
        dp0 += __shfl_xor(dp0, 4);
        dp0 += __shfl_xor(dp0, 8);
        dp1 += __shfl_xor(dp1, 1);
        dp1 += __shfl_xor(dp1, 2);
        dp1 += __shfl_xor(dp1, 4);
        dp1 += __shfl_xor(dp1, 8);
        float d0 = 0.125f * w * dp0;               // (e^-0.25)^2 = 1/8
        float d1 = 0.125f * w * dp1;
        uint4 v4 = *(const uint4*)((const ushort*)vu + off);
        float vf[8] = { bflo(v4.x), bfhi(v4.x), bflo(v4.y), bfhi(v4.y),
                        bflo(v4.z), bfhi(v4.z), bflo(v4.w), bfhi(v4.w) };
        float nm0 = fmaxf(m0, d0), c0 = __expf(m0 - nm0), t0 = __expf(d0 - nm0);
        float nm1 = fmaxf(m1, d1), c1 = __expf(m1 - nm1), t1 = __expf(d1 - nm1);
        s0 = s0 * c0 + t0; m0 = nm0;
        s1 = s1 * c1 + t1; m1 = nm1;
        #pragma unroll
        for (int u = 0; u < 4; ++u) av[u] = av[u] * c0 + t0 * vf[u];
        #pragma unroll
        for (int u = 4; u < 8; ++u) av[u] = av[u] * c1 + t1 * vf[u];
    }

    float i0 = (p1 > p0) ? (1.f / s0) : 0.f;
    float i1 = (p1 > p0) ? (1.f / s1) : 0.f;
    float res[4];
    #pragma unroll
    for (int u = 0; u < 4; ++u) {
        float v = av[u] * i0 + av[u + 4] * i1;     // sum the group's two heads
        v += __shfl_xor(v, 16);                    // sum over the 4 groups (8 heads)
        v += __shfl_xor(v, 32);
        res[u] = v;
    }
    if (lane < 16) {
        #pragma unroll
        for (int u = 0; u < 4; ++u)
            out[(size_t)gr * E + u * 16 + lane] = res[u] + bu[u * 16 + lane];
    }
}

extern "C" void kernel_launch(void* const* d_in, const int* in_sizes, int n_in,
                              void* d_out, int out_size, void* d_ws, size_t ws_size,
                              hipStream_t stream) {
    const float* x        = (const float*)d_in[0];
    const float* Wq       = (const float*)d_in[1];
    const float* Wk       = (const float*)d_in[2];
    const float* Wv       = (const float*)d_in[3];
    const float* Wu       = (const float*)d_in[4];
    const float* bu       = (const float*)d_in[5];
    const float* means_p  = (const float*)d_in[6];
    const float* sigmas_p = (const float*)d_in[7];
    const int*   g_ints   = (const int*)d_in[8];
    const int*   l_offs   = (const int*)d_in[9];
    float* out = (float*)d_out;

    char* ws = (char*)d_ws;
    size_t o = 0;
    auto alloc = [&](size_t bytes) -> void* {
        void* p = ws + o;
        o += (bytes + 255) & ~(size_t)255;
        return p;
    };
    __hip_bfloat16* q   = (__hip_bfloat16*)alloc((size_t)B * T * NH * 2);
    __hip_bfloat16* kk  = (__hip_bfloat16*)alloc((size_t)B * T * NH * 2);
    __hip_bfloat16* vu  = (__hip_bfloat16*)alloc((size_t)B * T * NH * 2);
    ushort* xb    = (ushort*)alloc((size_t)B * T * E * 2);
    ushort* wfrag = (ushort*)alloc((size_t)3 * 32 * 2 * 64 * 8 * 2);
    float* Wvu    = (float*)alloc((size_t)E * NH * 4);
    float* meansf = (float*)alloc(KP * 2 * 4);
    float* sigt   = (float*)alloc(KP * 4);
    int*   idxrow = (int*)alloc((size_t)B * VS * 4);
    int*   idxcol = (int*)alloc((size_t)B * VS * 4);
    float* wts    = (float*)alloc((size_t)B * VS * 4);
    int*   lrank  = (int*)alloc((size_t)B * VS * 4);
    int*   dup    = (int*)alloc((size_t)B * VS * 4);
    float* colsum = (float*)alloc((size_t)B * KP * 4);
    int*   rowcnt = (int*)alloc((size_t)B * T * 4);
    int*   rowptr = (int*)alloc((size_t)B * (T + 1) * 4);
    int*   scol   = (int*)alloc((size_t)B * VS * 4);
    float* sw     = (float*)alloc((size_t)B * VS * 4);
    int*   hkey   = (int*)alloc((size_t)B * HSZ * 4);
    int*   hval   = (int*)alloc((size_t)B * HSZ * 4);
    int*   chist  = (int*)alloc((size_t)B * T * NCHUNK * 4);

    hipMemsetAsync(hkey, 0xFF, (size_t)B * HSZ * 4, stream);       // keys = -1
    hipMemsetAsync(hval, 0x7F, (size_t)B * HSZ * 4, stream);       // vals = big
    hipMemsetAsync(chist, 0, (size_t)B * T * NCHUNK * 4, stream);

    k_points<<<1, 256, 0, stream>>>(means_p, sigmas_p, meansf, sigt);
    k_wvu<<<(E * NH + 255) / 256, 256, 0, stream>>>(Wv, Wu, Wvu);
    k_prep_x<<<(B * T * E / 8) / 256, 256, 0, stream>>>(x, xb);
    k_prep_w<<<(3 * 32 * 2 * 64 + 255) / 256, 256, 0, stream>>>(Wq, Wk, Wvu, wfrag);
    k_build_idx<<<B, 256, 0, stream>>>(g_ints, l_offs, meansf, idxrow, idxcol, hkey, hval);
    k_local<<<dim3(VS / 1024, B), 256, 0, stream>>>(idxrow, idxcol, hkey, hval, lrank, dup, chist);
    k_chunkscan<<<B * T / 256, 256, 0, stream>>>(chist, rowcnt);
    k_colsum<<<dim3(KP, B), 256, 0, stream>>>(idxrow, idxcol, dup, meansf, sigt, colsum);
    k_weights<<<dim3(VS / 256, B), 256, 0, stream>>>(idxrow, idxcol, dup, meansf, sigt, colsum, wts);
    k_scan<<<B, 1024, 0, stream>>>(rowcnt, rowptr);
    k_scatter<<<dim3(VS / 256, B), 256, 0, stream>>>(idxrow, idxcol, wts, lrank, chist, rowptr, scol, sw);
    k_proj<<<dim3(B * T / 64, 3), 256, 0, stream>>>(xb, wfrag, q, kk, vu);
    k_attn<<<B * T / 4, 256, 0, stream>>>(q, kk, vu, rowptr, scol, sw, bu, out);
}

// Round 5
// 191.638 us; speedup vs baseline: 2.4588x; 1.1968x over previous
//
#include <hip/hip_runtime.h>
#include <hip/hip_bf16.h>
#include <math.h>

#define B 16
#define T 4096
#define E 64
#define H 8
#define KP 256
#define GADD 8
#define RADD 8
#define REGION 64
#define VS (KP * (4 + GADD + RADD))   // 5120
#define NH (H * E)                    // 512
#define NCHUNK 20                     // VS / 256
#define HSZ 16384                     // hash slots per batch

typedef __attribute__((ext_vector_type(8))) short bf16x8;
typedef __attribute__((ext_vector_type(4))) float f32x4;

__device__ inline ushort f2bf(float f) {
    union { __hip_bfloat16 h; ushort u; } cv;
    cv.h = __float2bfloat16(f);
    return cv.u;
}
__device__ inline float bflo(uint32_t p) { return __uint_as_float(p << 16); }
__device__ inline float bfhi(uint32_t p) { return __uint_as_float(p & 0xffff0000u); }

// ---- K points: flip -> sigmoid*(t-1) means; softplus sigmas ----
__global__ void k_points(const float* __restrict__ means_p, const float* __restrict__ sigmas_p,
                         float* __restrict__ meansf, float* __restrict__ sigt) {
    int k = threadIdx.x;
    if (k >= KP) return;
    float a = means_p[2 * k], b = means_p[2 * k + 1];
    float hi = fmaxf(a, b), lo = fminf(a, b);
    meansf[2 * k]     = (1.f / (1.f + expf(-hi))) * (float)(T - 1);
    meansf[2 * k + 1] = (1.f / (1.f + expf(-lo))) * (float)(T - 1);
    float sp = sigmas_p[k] + 2.0f;
    float s = (sp > 20.f) ? sp : log1pf(expf(sp));
    sigt[k] = (s + 0.05f) * (float)T;
}

// ---- Wvu_h = Wv_h @ Wu_h  (fold output projection into V) ----
__global__ void k_wvu(const float* __restrict__ Wv, const float* __restrict__ Wu,
                      float* __restrict__ Wvu) {
    int idx = blockIdx.x * blockDim.x + threadIdx.x;
    if (idx >= E * NH) return;
    int i = idx / NH, c = idx % NH;
    int h = c / E, j = c % E;
    float acc = 0.f;
    for (int d = 0; d < E; ++d)
        acc += Wv[i * NH + h * E + d] * Wu[(h * E + d) * E + j];
    Wvu[i * NH + c] = acc;
}

// ---- x f32 -> bf16 ----
__global__ void k_prep_x(const float* __restrict__ x, ushort* __restrict__ xb) {
    int i = (blockIdx.x * 256 + threadIdx.x) * 8;
    float4 a = *(const float4*)(x + i);
    float4 b = *(const float4*)(x + i + 4);
    uint4 r;
    r.x = (uint32_t)f2bf(a.x) | ((uint32_t)f2bf(a.y) << 16);
    r.y = (uint32_t)f2bf(a.z) | ((uint32_t)f2bf(a.w) << 16);
    r.z = (uint32_t)f2bf(b.x) | ((uint32_t)f2bf(b.y) << 16);
    r.w = (uint32_t)f2bf(b.z) | ((uint32_t)f2bf(b.w) << 16);
    *(uint4*)(xb + i) = r;
}

// ---- pre-pack W into MFMA B-fragment lane order (bf16) ----
__global__ void k_prep_w(const float* __restrict__ Wq, const float* __restrict__ Wk,
                         const float* __restrict__ Wvu, ushort* __restrict__ wfrag) {
    int t = blockIdx.x * 256 + threadIdx.x;
    if (t >= 3 * 32 * 2 * 64) return;
    int lane = t & 63, kf = (t >> 6) & 1, nf = (t >> 7) & 31, z = t >> 12;
    const float* W = (z == 0) ? Wq : (z == 1) ? Wk : Wvu;
    int col = nf * 16 + (lane & 15);
    int krow = kf * 32 + (lane >> 4) * 8;
    uint4 r;
    uint32_t v[8];
    #pragma unroll
    for (int j = 0; j < 8; ++j) v[j] = f2bf(W[(size_t)(krow + j) * NH + col]);
    r.x = v[0] | (v[1] << 16); r.y = v[2] | (v[3] << 16);
    r.z = v[4] | (v[5] << 16); r.w = v[6] | (v[7] << 16);
    *(uint4*)(wfrag + (size_t)t * 8) = r;
}

// ---- MFMA projection: out_z = xb @ W_z, bf16, no LDS, coalesced 16B stores ----
// Output layout is PERMUTED within each 128-col block:
//   stored position p = wv*128 + (lane&15)*8 + nf  <->  orig col = wv*128 + nf*16 + (lane&15)
__global__ __launch_bounds__(256) void k_proj(const ushort* __restrict__ xb,
        const ushort* __restrict__ wfrag,
        __hip_bfloat16* __restrict__ q, __hip_bfloat16* __restrict__ kk,
        __hip_bfloat16* __restrict__ vu) {
    int z = blockIdx.y;
    __hip_bfloat16* outp = (z == 0) ? q : (z == 1) ? kk : vu;
    int row0 = blockIdx.x * 64;
    int wv = threadIdx.x >> 6, lane = threadIdx.x & 63;
    int arow = lane & 15, akoff = (lane >> 4) * 8;

    bf16x8 bfr[8][2];
    #pragma unroll
    for (int nf = 0; nf < 8; ++nf) {
        size_t base = ((size_t)((z * 32 + wv * 8 + nf) * 2) * 64 + lane) * 8;
        bfr[nf][0] = *(const bf16x8*)(wfrag + base);
        bfr[nf][1] = *(const bf16x8*)(wfrag + base + 64 * 8);
    }

    #pragma unroll
    for (int mf = 0; mf < 4; ++mf) {
        bf16x8 a0 = *(const bf16x8*)(xb + (size_t)(row0 + mf * 16 + arow) * 64 + akoff);
        bf16x8 a1 = *(const bf16x8*)(xb + (size_t)(row0 + mf * 16 + arow) * 64 + 32 + akoff);
        f32x4 acc[8];
        #pragma unroll
        for (int nf = 0; nf < 8; ++nf) {
            f32x4 t = {0.f, 0.f, 0.f, 0.f};
            t = __builtin_amdgcn_mfma_f32_16x16x32_bf16(a0, bfr[nf][0], t, 0, 0, 0);
            t = __builtin_amdgcn_mfma_f32_16x16x32_bf16(a1, bfr[nf][1], t, 0, 0, 0);
            acc[nf] = t;
        }
        int rbase = row0 + mf * 16 + (lane >> 4) * 4;
        #pragma unroll
        for (int rg = 0; rg < 4; ++rg) {
            uint4 o;
            o.x = (uint32_t)f2bf(acc[0][rg]) | ((uint32_t)f2bf(acc[1][rg]) << 16);
            o.y = (uint32_t)f2bf(acc[2][rg]) | ((uint32_t)f2bf(acc[3][rg]) << 16);
            o.z = (uint32_t)f2bf(acc[4][rg]) | ((uint32_t)f2bf(acc[5][rg]) << 16);
            o.w = (uint32_t)f2bf(acc[6][rg]) | ((uint32_t)f2bf(acc[7][rg]) << 16);
            *(uint4*)((ushort*)outp + (size_t)(rbase + rg) * NH + wv * 128 + (lane & 15) * 8) = o;
        }
    }
}

// ---- build sparse index tuples (flipped: row >= col) + hash insert ----
// one thread per (b, s): 320 blocks -> latency-hiding across 80K threads
__global__ void k_build_idx(const int* __restrict__ g_ints, const int* __restrict__ l_offs,
                            const float* __restrict__ meansf,
                            int* __restrict__ idxrow, int* __restrict__ idxcol,
                            int* __restrict__ hkey, int* __restrict__ hval) {
    int b = blockIdx.y;
    int s = blockIdx.x * 256 + threadIdx.x;
    int* keys = hkey + b * HSZ;
    int* vals = hval + b * HSZ;
    int k = s / 20, slot = s % 20;
    float m0 = meansf[2 * k], m1 = meansf[2 * k + 1];
    int i0, i1;
    if (slot < 4) {
        float a  = (slot & 2) ? ceilf(m0) : floorf(m0);
        float bb = (slot & 1) ? ceilf(m1) : floorf(m1);
        a  = fminf(fmaxf(a, 0.f), (float)(T - 1));
        bb = fminf(fmaxf(bb, 0.f), (float)(T - 1));
        i0 = (int)a; i1 = (int)bb;
    } else if (slot < 12) {
        const int* p = g_ints + ((size_t)((b * KP + k) * GADD) + (slot - 4)) * 2;
        i0 = p[0]; i1 = p[1];
    } else {
        int lo0 = (int)fminf(fmaxf(floorf(m0) - (float)(REGION / 2), 0.f), (float)(T - REGION));
        int lo1 = (int)fminf(fmaxf(floorf(m1) - (float)(REGION / 2), 0.f), (float)(T - REGION));
        const int* p = l_offs + ((size_t)((b * KP + k) * RADD) + (slot - 12)) * 2;
        i0 = lo0 + p[0]; i1 = lo1 + p[1];
    }
    int row = max(i0, i1), col = min(i0, i1);
    idxrow[b * VS + s] = row;
    idxcol[b * VS + s] = col;
    // hash insert: min original index per id. Slot placement may vary with
    // timing, but lookups probe to key-match and atomicMin is order-free ->
    // deterministic dup[] regardless of scheduling.
    int id = row * T + col;
    unsigned h = ((unsigned)id * 2654435761u) >> 18;
    while (true) {
        int old = atomicCAS(&keys[h], -1, id);
        if (old == -1 || old == id) { atomicMin(&vals[h], s); break; }
        h = (h + 1) & (HSZ - 1);
    }
}

// ---- per-chunk local rank (shuffles) + chunk histogram + dup lookup ----
__global__ __launch_bounds__(256) void k_local(const int* __restrict__ idxrow,
        const int* __restrict__ idxcol, const int* __restrict__ hkey,
        const int* __restrict__ hval, int* __restrict__ lrank, int* __restrict__ dup,
        int* __restrict__ chist) {
    int b = blockIdx.y;
    int wv = threadIdx.x >> 6, lane = threadIdx.x & 63;
    int chunk = blockIdx.x * 4 + wv;
    int s0 = chunk * 256 + lane;
    int r0 = idxrow[b * VS + s0];
    int r1 = idxrow[b * VS + s0 + 64];
    int r2 = idxrow[b * VS + s0 + 128];
    int r3 = idxrow[b * VS + s0 + 192];
    int lr0 = 0, lr1 = 0, lr2 = 0, lr3 = 0;
    #pragma unroll
    for (int j = 0; j < 64; ++j) {
        int a0 = __shfl(r0, j), a1 = __shfl(r1, j), a2 = __shfl(r2, j), a3 = __shfl(r3, j);
        bool lt = (j < lane);
        lr0 += (lt && a0 == r0);
        lr1 += (a0 == r1) + (lt && a1 == r1);
        lr2 += (a0 == r2) + (a1 == r2) + (lt && a2 == r2);
        lr3 += (a0 == r3) + (a1 == r3) + (a2 == r3) + (lt && a3 == r3);
    }
    lrank[b * VS + s0]       = lr0;
    lrank[b * VS + s0 + 64]  = lr1;
    lrank[b * VS + s0 + 128] = lr2;
    lrank[b * VS + s0 + 192] = lr3;
    atomicAdd(&chist[(size_t)(b * T + r0) * NCHUNK + chunk], 1);
    atomicAdd(&chist[(size_t)(b * T + r1) * NCHUNK + chunk], 1);
    atomicAdd(&chist[(size_t)(b * T + r2) * NCHUNK + chunk], 1);
    atomicAdd(&chist[(size_t)(b * T + r3) * NCHUNK + chunk], 1);
    const int* keys = hkey + b * HSZ;
    const int* vals = hval + b * HSZ;
    #pragma unroll
    for (int i = 0; i < 4; ++i) {
        int s = s0 + i * 64;
        int id = idxrow[b * VS + s] * T + idxcol[b * VS + s];
        unsigned h = ((unsigned)id * 2654435761u) >> 18;
        while (keys[h] != id) h = (h + 1) & (HSZ - 1);
        dup[b * VS + s] = (vals[h] != s);
    }
}

// ---- per-(b,row): exclusive prefix over chunks, total -> rowcnt ----
__global__ void k_chunkscan(int* __restrict__ chist, int* __restrict__ rowcnt) {
    int idx = blockIdx.x * 256 + threadIdx.x;   // b*T + row
    int* p = chist + (size_t)idx * NCHUNK;
    int acc = 0;
    #pragma unroll
    for (int c = 0; c < NCHUNK; ++c) { int v = p[c]; p[c] = acc; acc += v; }
    rowcnt[idx] = acc;
}

// ---- column sums of the (non-dup) density matrix ----
__global__ void k_colsum(const int* __restrict__ idxrow, const int* __restrict__ idxcol,
                         const int* __restrict__ dup, const float* __restrict__ meansf,
                         const float* __restrict__ sigt, float* __restrict__ colsum) {
    int k = blockIdx.x, b = blockIdx.y;
    float m0 = meansf[2 * k], m1 = meansf[2 * k + 1];
    float inv = 1.f / sigt[k];
    float acc = 0.f;
    for (int s = threadIdx.x; s < VS; s += 256) {
        if (!dup[b * VS + s]) {
            float d0 = ((float)idxrow[b * VS + s] - m0) * inv;
            float d1 = ((float)idxcol[b * VS + s] - m1) * inv;
            acc += __expf(-0.5f * (d0 * d0 + d1 * d1));
        }
    }
    __shared__ float red[256];
    red[threadIdx.x] = acc;
    __syncthreads();
    for (int o = 128; o > 0; o >>= 1) {
        if (threadIdx.x < o) red[threadIdx.x] += red[threadIdx.x + o];
        __syncthreads();
    }
    if (threadIdx.x == 0) colsum[b * KP + k] = red[0];
}

// ---- per-entry weight = sum_k prop/colsum_k ----
__global__ void k_weights(const int* __restrict__ idxrow, const int* __restrict__ idxcol,
                          const int* __restrict__ dup, const float* __restrict__ meansf,
                          const float* __restrict__ sigt, const float* __restrict__ colsum,
                          float* __restrict__ wts) {
    int b = blockIdx.y;
    int s = blockIdx.x * 256 + threadIdx.x;
    __shared__ float sm[2 * KP], ss[KP], rc[KP];
    for (int k = threadIdx.x; k < KP; k += 256) {
        sm[2 * k] = meansf[2 * k];
        sm[2 * k + 1] = meansf[2 * k + 1];
        ss[k] = 1.f / sigt[k];
        rc[k] = 1.f / colsum[b * KP + k];
    }
    __syncthreads();
    float w = 0.f;
    if (!dup[b * VS + s]) {
        float r = (float)idxrow[b * VS + s], c = (float)idxcol[b * VS + s];
        #pragma unroll 4
        for (int k = 0; k < KP; ++k) {
            float d0 = (r - sm[2 * k]) * ss[k];
            float d1 = (c - sm[2 * k + 1]) * ss[k];
            w += __expf(-0.5f * (d0 * d0 + d1 * d1)) * rc[k];
        }
    }
    wts[b * VS + s] = w;
}

// ---- exclusive prefix sum per batch (4096 rows) ----
__global__ __launch_bounds__(1024) void k_scan(const int* __restrict__ rowcnt, int* __restrict__ rowptr) {
    int b = blockIdx.x, tid = threadIdx.x;
    __shared__ int part[1024];
    int v[4]; int loc = 0;
    for (int j = 0; j < 4; ++j) { v[j] = rowcnt[b * T + tid * 4 + j]; loc += v[j]; }
    part[tid] = loc;
    __syncthreads();
    for (int off = 1; off < 1024; off <<= 1) {
        int t = (tid >= off) ? part[tid - off] : 0;
        __syncthreads();
        part[tid] += t;
        __syncthreads();
    }
    int excl = part[tid] - loc;
    for (int j = 0; j < 4; ++j) { rowptr[b * (T + 1) + tid * 4 + j] = excl; excl += v[j]; }
    if (tid == 1023) rowptr[b * (T + 1) + T] = part[1023];
}

// ---- deterministic counting-sort scatter ----
__global__ void k_scatter(const int* __restrict__ idxrow, const int* __restrict__ idxcol,
                          const float* __restrict__ wts, const int* __restrict__ lrank,
                          const int* __restrict__ chist, const int* __restrict__ rowptr,
                          int* __restrict__ scol, float* __restrict__ sw) {
    int b = blockIdx.y;
    int s = blockIdx.x * 256 + threadIdx.x;
    int r = idxrow[b * VS + s];
    int pos = rowptr[b * (T + 1) + r] + chist[(size_t)(b * T + r) * NCHUNK + (s >> 8)]
            + lrank[b * VS + s];
    scol[b * VS + pos] = idxcol[b * VS + s];
    sw[b * VS + pos] = wts[b * VS + s];
}

// ---- attention over permuted layout: wave per row; 16-lane group blk handles
// heads 2*blk (regs 0-3) and 2*blk+1 (regs 4-7); feature j = (u%4)*16 + (lane&15) ----
__global__ __launch_bounds__(256) void k_attn(
        const __hip_bfloat16* __restrict__ q, const __hip_bfloat16* __restrict__ kk,
        const __hip_bfloat16* __restrict__ vu, const int* __restrict__ rowptr,
        const int* __restrict__ scol, const float* __restrict__ sw,
        const float* __restrict__ bu, float* __restrict__ out) {
    int gr = blockIdx.x * 4 + (threadIdx.x >> 6);   // b*T + r
    int b = gr >> 12;
    int r = gr & (T - 1);
    int lane = threadIdx.x & 63;
    int p0 = rowptr[b * (T + 1) + r], p1 = rowptr[b * (T + 1) + r + 1];

    uint4 q4 = *(const uint4*)((const ushort*)q + (size_t)gr * NH + lane * 8);
    float qv[8] = { bflo(q4.x), bfhi(q4.x), bflo(q4.y), bfhi(q4.y),
                    bflo(q4.z), bfhi(q4.z), bflo(q4.w), bfhi(q4.w) };

    float m0 = -INFINITY, s0 = 0.f, m1 = -INFINITY, s1 = 0.f;
    float av[8] = {0.f,0.f,0.f,0.f,0.f,0.f,0.f,0.f};

    for (int e = p0; e < p1; ++e) {
        int c = scol[b * VS + e];
        float w = sw[b * VS + e];
        size_t off = ((size_t)(b * T + c)) * NH + lane * 8;
        uint4 k4 = *(const uint4*)((const ushort*)kk + off);
        float dp0 = qv[0]*bflo(k4.x) + qv[1]*bfhi(k4.x) + qv[2]*bflo(k4.y) + qv[3]*bfhi(k4.y);
        float dp1 = qv[4]*bflo(k4.z) + qv[5]*bfhi(k4.z) + qv[6]*bflo(k4.w) + qv[7]*bfhi(k4.w);
        dp0 += __shfl_xor(dp0, 1);
        dp0 += __shfl_xor(dp0, 2);
        dp0 += __shfl_xor(dp0, 4);
        dp0 += __shfl_xor(dp0, 8);
        dp1 += __shfl_xor(dp1, 1);
        dp1 += __shfl_xor(dp1, 2);
        dp1 += __shfl_xor(dp1, 4);
        dp1 += __shfl_xor(dp1, 8);
        float d0 = 0.125f * w * dp0;               // (e^-0.25)^2 = 1/8
        float d1 = 0.125f * w * dp1;
        uint4 v4 = *(const uint4*)((const ushort*)vu + off);
        float vf[8] = { bflo(v4.x), bfhi(v4.x), bflo(v4.y), bfhi(v4.y),
                        bflo(v4.z), bfhi(v4.z), bflo(v4.w), bfhi(v4.w) };
        float nm0 = fmaxf(m0, d0), c0 = __expf(m0 - nm0), t0 = __expf(d0 - nm0);
        float nm1 = fmaxf(m1, d1), c1 = __expf(m1 - nm1), t1 = __expf(d1 - nm1);
        s0 = s0 * c0 + t0; m0 = nm0;
        s1 = s1 * c1 + t1; m1 = nm1;
        #pragma unroll
        for (int u = 0; u < 4; ++u) av[u] = av[u] * c0 + t0 * vf[u];
        #pragma unroll
        for (int u = 4; u < 8; ++u) av[u] = av[u] * c1 + t1 * vf[u];
    }

    float i0 = (p1 > p0) ? (1.f / s0) : 0.f;
    float i1 = (p1 > p0) ? (1.f / s1) : 0.f;
    float res[4];
    #pragma unroll
    for (int u = 0; u < 4; ++u) {
        float v = av[u] * i0 + av[u + 4] * i1;     // sum the group's two heads
        v += __shfl_xor(v, 16);                    // sum over the 4 groups (8 heads)
        v += __shfl_xor(v, 32);
        res[u] = v;
    }
    if (lane < 16) {
        #pragma unroll
        for (int u = 0; u < 4; ++u)
            out[(size_t)gr * E + u * 16 + lane] = res[u] + bu[u * 16 + lane];
    }
}

extern "C" void kernel_launch(void* const* d_in, const int* in_sizes, int n_in,
                              void* d_out, int out_size, void* d_ws, size_t ws_size,
                              hipStream_t stream) {
    const float* x        = (const float*)d_in[0];
    const float* Wq       = (const float*)d_in[1];
    const float* Wk       = (const float*)d_in[2];
    const float* Wv       = (const float*)d_in[3];
    const float* Wu       = (const float*)d_in[4];
    const float* bu       = (const float*)d_in[5];
    const float* means_p  = (const float*)d_in[6];
    const float* sigmas_p = (const float*)d_in[7];
    const int*   g_ints   = (const int*)d_in[8];
    const int*   l_offs   = (const int*)d_in[9];
    float* out = (float*)d_out;

    char* ws = (char*)d_ws;
    size_t o = 0;
    auto alloc = [&](size_t bytes) -> void* {
        void* p = ws + o;
        o += (bytes + 255) & ~(size_t)255;
        return p;
    };
    __hip_bfloat16* q   = (__hip_bfloat16*)alloc((size_t)B * T * NH * 2);
    __hip_bfloat16* kk  = (__hip_bfloat16*)alloc((size_t)B * T * NH * 2);
    __hip_bfloat16* vu  = (__hip_bfloat16*)alloc((size_t)B * T * NH * 2);
    ushort* xb    = (ushort*)alloc((size_t)B * T * E * 2);
    ushort* wfrag = (ushort*)alloc((size_t)3 * 32 * 2 * 64 * 8 * 2);
    float* Wvu    = (float*)alloc((size_t)E * NH * 4);
    float* meansf = (float*)alloc(KP * 2 * 4);
    float* sigt   = (float*)alloc(KP * 4);
    int*   idxrow = (int*)alloc((size_t)B * VS * 4);
    int*   idxcol = (int*)alloc((size_t)B * VS * 4);
    float* wts    = (float*)alloc((size_t)B * VS * 4);
    int*   lrank  = (int*)alloc((size_t)B * VS * 4);
    int*   dup    = (int*)alloc((size_t)B * VS * 4);
    float* colsum = (float*)alloc((size_t)B * KP * 4);
    int*   rowcnt = (int*)alloc((size_t)B * T * 4);
    int*   rowptr = (int*)alloc((size_t)B * (T + 1) * 4);
    int*   scol   = (int*)alloc((size_t)B * VS * 4);
    float* sw     = (float*)alloc((size_t)B * VS * 4);
    int*   hkey   = (int*)alloc((size_t)B * HSZ * 4);
    int*   hval   = (int*)alloc((size_t)B * HSZ * 4);
    int*   chist  = (int*)alloc((size_t)B * T * NCHUNK * 4);

    hipMemsetAsync(hkey, 0xFF, (size_t)B * HSZ * 4, stream);       // keys = -1
    hipMemsetAsync(hval, 0x7F, (size_t)B * HSZ * 4, stream);       // vals = big
    hipMemsetAsync(chist, 0, (size_t)B * T * NCHUNK * 4, stream);

    k_points<<<1, 256, 0, stream>>>(means_p, sigmas_p, meansf, sigt);
    k_wvu<<<(E * NH + 255) / 256, 256, 0, stream>>>(Wv, Wu, Wvu);
    k_prep_x<<<(B * T * E / 8) / 256, 256, 0, stream>>>(x, xb);
    k_prep_w<<<(3 * 32 * 2 * 64 + 255) / 256, 256, 0, stream>>>(Wq, Wk, Wvu, wfrag);
    k_build_idx<<<dim3(VS / 256, B), 256, 0, stream>>>(g_ints, l_offs, meansf, idxrow, idxcol, hkey, hval);
    k_local<<<dim3(VS / 1024, B), 256, 0, stream>>>(idxrow, idxcol, hkey, hval, lrank, dup, chist);
    k_chunkscan<<<B * T / 256, 256, 0, stream>>>(chist, rowcnt);
    k_colsum<<<dim3(KP, B), 256, 0, stream>>>(idxrow, idxcol, dup, meansf, sigt, colsum);
    k_weights<<<dim3(VS / 256, B), 256, 0, stream>>>(idxrow, idxcol, dup, meansf, sigt, colsum, wts);
    k_scan<<<B, 1024, 0, stream>>>(rowcnt, rowptr);
    k_scatter<<<dim3(VS / 256, B), 256, 0, stream>>>(idxrow, idxcol, wts, lrank, chist, rowptr, scol, sw);
    k_proj<<<dim3(B * T / 64, 3), 256, 0, stream>>>(xb, wfrag, q, kk, vu);
    k_attn<<<B * T / 4, 256, 0, stream>>>(q, kk, vu, rowptr, scol, sw, bu, out);
}

// Round 6
// 182.809 us; speedup vs baseline: 2.5776x; 1.0483x over previous
//
#include <hip/hip_runtime.h>
#include <hip/hip_bf16.h>
#include <math.h>

#define B 16
#define T 4096
#define E 64
#define H 8
#define KP 256
#define GADD 8
#define RADD 8
#define REGION 64
#define VS (KP * (4 + GADD + RADD))   // 5120
#define NH (H * E)                    // 512
#define NCHUNK 20                     // VS / 256
#define HSZ 16384                     // hash slots per batch

typedef __attribute__((ext_vector_type(8))) short bf16x8;
typedef __attribute__((ext_vector_type(4))) float f32x4;

__device__ inline ushort f2bf(float f) {
    union { __hip_bfloat16 h; ushort u; } cv;
    cv.h = __float2bfloat16(f);
    return cv.u;
}
__device__ inline float bflo(uint32_t p) { return __uint_as_float(p << 16); }
__device__ inline float bfhi(uint32_t p) { return __uint_as_float(p & 0xffff0000u); }

// ---- K points: flip -> sigmoid*(t-1) means; softplus sigmas ----
__global__ void k_points(const float* __restrict__ means_p, const float* __restrict__ sigmas_p,
                         float* __restrict__ meansf, float* __restrict__ sigt) {
    int k = threadIdx.x;
    if (k >= KP) return;
    float a = means_p[2 * k], b = means_p[2 * k + 1];
    float hi = fmaxf(a, b), lo = fminf(a, b);
    meansf[2 * k]     = (1.f / (1.f + expf(-hi))) * (float)(T - 1);
    meansf[2 * k + 1] = (1.f / (1.f + expf(-lo))) * (float)(T - 1);
    float sp = sigmas_p[k] + 2.0f;
    float s = (sp > 20.f) ? sp : log1pf(expf(sp));
    sigt[k] = (s + 0.05f) * (float)T;
}

// ---- Wvu_h = Wv_h @ Wu_h  (fold output projection into V) ----
__global__ void k_wvu(const float* __restrict__ Wv, const float* __restrict__ Wu,
                      float* __restrict__ Wvu) {
    int idx = blockIdx.x * blockDim.x + threadIdx.x;
    if (idx >= E * NH) return;
    int i = idx / NH, c = idx % NH;
    int h = c / E, j = c % E;
    float acc = 0.f;
    for (int d = 0; d < E; ++d)
        acc += Wv[i * NH + h * E + d] * Wu[(h * E + d) * E + j];
    Wvu[i * NH + c] = acc;
}

// ---- x f32 -> bf16 ----
__global__ void k_prep_x(const float* __restrict__ x, ushort* __restrict__ xb) {
    int i = (blockIdx.x * 256 + threadIdx.x) * 8;
    float4 a = *(const float4*)(x + i);
    float4 b = *(const float4*)(x + i + 4);
    uint4 r;
    r.x = (uint32_t)f2bf(a.x) | ((uint32_t)f2bf(a.y) << 16);
    r.y = (uint32_t)f2bf(a.z) | ((uint32_t)f2bf(a.w) << 16);
    r.z = (uint32_t)f2bf(b.x) | ((uint32_t)f2bf(b.y) << 16);
    r.w = (uint32_t)f2bf(b.z) | ((uint32_t)f2bf(b.w) << 16);
    *(uint4*)(xb + i) = r;
}

// ---- pre-pack W into MFMA B-fragment lane order (bf16) ----
__global__ void k_prep_w(const float* __restrict__ Wq, const float* __restrict__ Wk,
                         const float* __restrict__ Wvu, ushort* __restrict__ wfrag) {
    int t = blockIdx.x * 256 + threadIdx.x;
    if (t >= 3 * 32 * 2 * 64) return;
    int lane = t & 63, kf = (t >> 6) & 1, nf = (t >> 7) & 31, z = t >> 12;
    const float* W = (z == 0) ? Wq : (z == 1) ? Wk : Wvu;
    int col = nf * 16 + (lane & 15);
    int krow = kf * 32 + (lane >> 4) * 8;
    uint4 r;
    uint32_t v[8];
    #pragma unroll
    for (int j = 0; j < 8; ++j) v[j] = f2bf(W[(size_t)(krow + j) * NH + col]);
    r.x = v[0] | (v[1] << 16); r.y = v[2] | (v[3] << 16);
    r.z = v[4] | (v[5] << 16); r.w = v[6] | (v[7] << 16);
    *(uint4*)(wfrag + (size_t)t * 8) = r;
}

// ---- MFMA projection: out_z = xb @ W_z, bf16, no LDS, coalesced 16B stores ----
// Output layout is PERMUTED within each 128-col block:
//   stored position p = wv*128 + (lane&15)*8 + nf  <->  orig col = wv*128 + nf*16 + (lane&15)
__global__ __launch_bounds__(256) void k_proj(const ushort* __restrict__ xb,
        const ushort* __restrict__ wfrag,
        __hip_bfloat16* __restrict__ q, __hip_bfloat16* __restrict__ kk,
        __hip_bfloat16* __restrict__ vu) {
    int z = blockIdx.y;
    __hip_bfloat16* outp = (z == 0) ? q : (z == 1) ? kk : vu;
    int row0 = blockIdx.x * 64;
    int wv = threadIdx.x >> 6, lane = threadIdx.x & 63;
    int arow = lane & 15, akoff = (lane >> 4) * 8;

    bf16x8 bfr[8][2];
    #pragma unroll
    for (int nf = 0; nf < 8; ++nf) {
        size_t base = ((size_t)((z * 32 + wv * 8 + nf) * 2) * 64 + lane) * 8;
        bfr[nf][0] = *(const bf16x8*)(wfrag + base);
        bfr[nf][1] = *(const bf16x8*)(wfrag + base + 64 * 8);
    }

    #pragma unroll
    for (int mf = 0; mf < 4; ++mf) {
        bf16x8 a0 = *(const bf16x8*)(xb + (size_t)(row0 + mf * 16 + arow) * 64 + akoff);
        bf16x8 a1 = *(const bf16x8*)(xb + (size_t)(row0 + mf * 16 + arow) * 64 + 32 + akoff);
        f32x4 acc[8];
        #pragma unroll
        for (int nf = 0; nf < 8; ++nf) {
            f32x4 t = {0.f, 0.f, 0.f, 0.f};
            t = __builtin_amdgcn_mfma_f32_16x16x32_bf16(a0, bfr[nf][0], t, 0, 0, 0);
            t = __builtin_amdgcn_mfma_f32_16x16x32_bf16(a1, bfr[nf][1], t, 0, 0, 0);
            acc[nf] = t;
        }
        int rbase = row0 + mf * 16 + (lane >> 4) * 4;
        #pragma unroll
        for (int rg = 0; rg < 4; ++rg) {
            uint4 o;
            o.x = (uint32_t)f2bf(acc[0][rg]) | ((uint32_t)f2bf(acc[1][rg]) << 16);
            o.y = (uint32_t)f2bf(acc[2][rg]) | ((uint32_t)f2bf(acc[3][rg]) << 16);
            o.z = (uint32_t)f2bf(acc[4][rg]) | ((uint32_t)f2bf(acc[5][rg]) << 16);
            o.w = (uint32_t)f2bf(acc[6][rg]) | ((uint32_t)f2bf(acc[7][rg]) << 16);
            *(uint4*)((ushort*)outp + (size_t)(rbase + rg) * NH + wv * 128 + (lane & 15) * 8) = o;
        }
    }
}

// ---- build sparse index tuples (flipped: row >= col) + hash insert ----
__global__ void k_build_idx(const int* __restrict__ g_ints, const int* __restrict__ l_offs,
                            const float* __restrict__ meansf,
                            int* __restrict__ idxrow, int* __restrict__ idxcol,
                            int* __restrict__ hkey, int* __restrict__ hval) {
    int b = blockIdx.y;
    int s = blockIdx.x * 256 + threadIdx.x;
    int* keys = hkey + b * HSZ;
    int* vals = hval + b * HSZ;
    int k = s / 20, slot = s % 20;
    float m0 = meansf[2 * k], m1 = meansf[2 * k + 1];
    int i0, i1;
    if (slot < 4) {
        float a  = (slot & 2) ? ceilf(m0) : floorf(m0);
        float bb = (slot & 1) ? ceilf(m1) : floorf(m1);
        a  = fminf(fmaxf(a, 0.f), (float)(T - 1));
        bb = fminf(fmaxf(bb, 0.f), (float)(T - 1));
        i0 = (int)a; i1 = (int)bb;
    } else if (slot < 12) {
        const int* p = g_ints + ((size_t)((b * KP + k) * GADD) + (slot - 4)) * 2;
        i0 = p[0]; i1 = p[1];
    } else {
        int lo0 = (int)fminf(fmaxf(floorf(m0) - (float)(REGION / 2), 0.f), (float)(T - REGION));
        int lo1 = (int)fminf(fmaxf(floorf(m1) - (float)(REGION / 2), 0.f), (float)(T - REGION));
        const int* p = l_offs + ((size_t)((b * KP + k) * RADD) + (slot - 12)) * 2;
        i0 = lo0 + p[0]; i1 = lo1 + p[1];
    }
    int row = max(i0, i1), col = min(i0, i1);
    idxrow[b * VS + s] = row;
    idxcol[b * VS + s] = col;
    // hash insert: min original index per id. Slot placement may vary with
    // timing, but lookups probe to key-match and atomicMin is order-free ->
    // deterministic dup[] regardless of scheduling.
    int id = row * T + col;
    unsigned h = ((unsigned)id * 2654435761u) >> 18;
    while (true) {
        int old = atomicCAS(&keys[h], -1, id);
        if (old == -1 || old == id) { atomicMin(&vals[h], s); break; }
        h = (h + 1) & (HSZ - 1);
    }
}

// ---- one block per 256-entry chunk: local rank via LDS broadcast loop,
// chunk histogram atomic, dup lookup. One thread per entry. ----
__global__ __launch_bounds__(256) void k_local(const int* __restrict__ idxrow,
        const int* __restrict__ idxcol, const int* __restrict__ hkey,
        const int* __restrict__ hval, int* __restrict__ lrank, int* __restrict__ dup,
        int* __restrict__ chist) {
    int b = blockIdx.y, chunk = blockIdx.x;
    int tid = threadIdx.x;
    int s = chunk * 256 + tid;
    int r = idxrow[b * VS + s];
    int c = idxcol[b * VS + s];
    __shared__ int srow[256];
    srow[tid] = r;
    __syncthreads();
    int lr = 0;
    #pragma unroll 8
    for (int t = 0; t < 256; ++t) {
        int rt = srow[t];                 // same addr across lanes -> broadcast
        lr += (t < tid && rt == r);
    }
    lrank[b * VS + s] = lr;
    atomicAdd(&chist[(size_t)(b * T + r) * NCHUNK + chunk], 1);
    const int* keys = hkey + b * HSZ;
    const int* vals = hval + b * HSZ;
    int id = r * T + c;
    unsigned h = ((unsigned)id * 2654435761u) >> 18;
    while (keys[h] != id) h = (h + 1) & (HSZ - 1);
    dup[b * VS + s] = (vals[h] != s);
}

// ---- per-(b,row): exclusive prefix over chunks, total -> rowcnt ----
__global__ void k_chunkscan(int* __restrict__ chist, int* __restrict__ rowcnt) {
    int idx = blockIdx.x * 256 + threadIdx.x;   // b*T + row
    int* p = chist + (size_t)idx * NCHUNK;
    int acc = 0;
    #pragma unroll
    for (int c = 0; c < NCHUNK; ++c) { int v = p[c]; p[c] = acc; acc += v; }
    rowcnt[idx] = acc;
}

// ---- column sums of the (non-dup) density matrix ----
__global__ void k_colsum(const int* __restrict__ idxrow, const int* __restrict__ idxcol,
                         const int* __restrict__ dup, const float* __restrict__ meansf,
                         const float* __restrict__ sigt, float* __restrict__ colsum) {
    int k = blockIdx.x, b = blockIdx.y;
    float m0 = meansf[2 * k], m1 = meansf[2 * k + 1];
    float inv = 1.f / sigt[k];
    float acc = 0.f;
    for (int s = threadIdx.x; s < VS; s += 256) {
        if (!dup[b * VS + s]) {
            float d0 = ((float)idxrow[b * VS + s] - m0) * inv;
            float d1 = ((float)idxcol[b * VS + s] - m1) * inv;
            acc += __expf(-0.5f * (d0 * d0 + d1 * d1));
        }
    }
    __shared__ float red[256];
    red[threadIdx.x] = acc;
    __syncthreads();
    for (int o = 128; o > 0; o >>= 1) {
        if (threadIdx.x < o) red[threadIdx.x] += red[threadIdx.x + o];
        __syncthreads();
    }
    if (threadIdx.x == 0) colsum[b * KP + k] = red[0];
}

// ---- per-entry weight = sum_k prop/colsum_k ----
__global__ void k_weights(const int* __restrict__ idxrow, const int* __restrict__ idxcol,
                          const int* __restrict__ dup, const float* __restrict__ meansf,
                          const float* __restrict__ sigt, const float* __restrict__ colsum,
                          float* __restrict__ wts) {
    int b = blockIdx.y;
    int s = blockIdx.x * 256 + threadIdx.x;
    __shared__ float sm[2 * KP], ss[KP], rc[KP];
    for (int k = threadIdx.x; k < KP; k += 256) {
        sm[2 * k] = meansf[2 * k];
        sm[2 * k + 1] = meansf[2 * k + 1];
        ss[k] = 1.f / sigt[k];
        rc[k] = 1.f / colsum[b * KP + k];
    }
    __syncthreads();
    float w = 0.f;
    if (!dup[b * VS + s]) {
        float r = (float)idxrow[b * VS + s], c = (float)idxcol[b * VS + s];
        #pragma unroll 4
        for (int k = 0; k < KP; ++k) {
            float d0 = (r - sm[2 * k]) * ss[k];
            float d1 = (c - sm[2 * k + 1]) * ss[k];
            w += __expf(-0.5f * (d0 * d0 + d1 * d1)) * rc[k];
        }
    }
    wts[b * VS + s] = w;
}

// ---- exclusive prefix sum per batch (4096 rows) ----
__global__ __launch_bounds__(1024) void k_scan(const int* __restrict__ rowcnt, int* __restrict__ rowptr) {
    int b = blockIdx.x, tid = threadIdx.x;
    __shared__ int part[1024];
    int v[4]; int loc = 0;
    for (int j = 0; j < 4; ++j) { v[j] = rowcnt[b * T + tid * 4 + j]; loc += v[j]; }
    part[tid] = loc;
    __syncthreads();
    for (int off = 1; off < 1024; off <<= 1) {
        int t = (tid >= off) ? part[tid - off] : 0;
        __syncthreads();
        part[tid] += t;
        __syncthreads();
    }
    int excl = part[tid] - loc;
    for (int j = 0; j < 4; ++j) { rowptr[b * (T + 1) + tid * 4 + j] = excl; excl += v[j]; }
    if (tid == 1023) rowptr[b * (T + 1) + T] = part[1023];
}

// ---- deterministic counting-sort scatter ----
__global__ void k_scatter(const int* __restrict__ idxrow, const int* __restrict__ idxcol,
                          const float* __restrict__ wts, const int* __restrict__ lrank,
                          const int* __restrict__ chist, const int* __restrict__ rowptr,
                          int* __restrict__ scol, float* __restrict__ sw) {
    int b = blockIdx.y;
    int s = blockIdx.x * 256 + threadIdx.x;
    int r = idxrow[b * VS + s];
    int pos = rowptr[b * (T + 1) + r] + chist[(size_t)(b * T + r) * NCHUNK + (s >> 8)]
            + lrank[b * VS + s];
    scol[b * VS + pos] = idxcol[b * VS + s];
    sw[b * VS + pos] = wts[b * VS + s];
}

// ---- attention over permuted layout: wave per row; 16-lane group blk handles
// heads 2*blk (regs 0-3) and 2*blk+1 (regs 4-7); feature j = (u%4)*16 + (lane&15) ----
__global__ __launch_bounds__(256) void k_attn(
        const __hip_bfloat16* __restrict__ q, const __hip_bfloat16* __restrict__ kk,
        const __hip_bfloat16* __restrict__ vu, const int* __restrict__ rowptr,
        const int* __restrict__ scol, const float* __restrict__ sw,
        const float* __restrict__ bu, float* __restrict__ out) {
    int gr = blockIdx.x * 4 + (threadIdx.x >> 6);   // b*T + r
    int b = gr >> 12;
    int r = gr & (T - 1);
    int lane = threadIdx.x & 63;
    int p0 = rowptr[b * (T + 1) + r], p1 = rowptr[b * (T + 1) + r + 1];

    uint4 q4 = *(const uint4*)((const ushort*)q + (size_t)gr * NH + lane * 8);
    float qv[8] = { bflo(q4.x), bfhi(q4.x), bflo(q4.y), bfhi(q4.y),
                    bflo(q4.z), bfhi(q4.z), bflo(q4.w), bfhi(q4.w) };

    float m0 = -INFINITY, s0 = 0.f, m1 = -INFINITY, s1 = 0.f;
    float av[8] = {0.f,0.f,0.f,0.f,0.f,0.f,0.f,0.f};

    for (int e = p0; e < p1; ++e) {
        int c = scol[b * VS + e];
        float w = sw[b * VS + e];
        size_t off = ((size_t)(b * T + c)) * NH + lane * 8;
        uint4 k4 = *(const uint4*)((const ushort*)kk + off);
        float dp0 = qv[0]*bflo(k4.x) + qv[1]*bfhi(k4.x) + qv[2]*bflo(k4.y) + qv[3]*bfhi(k4.y);
        float dp1 = qv[4]*bflo(k4.z) + qv[5]*bfhi(k4.z) + qv[6]*bflo(k4.w) + qv[7]*bfhi(k4.w);
        dp0 += __shfl_xor(dp0, 1);
        dp0 += __shfl_xor(dp0, 2);
        dp0 += __shfl_xor(dp0, 4);
        dp0 += __shfl_xor(dp0, 8);
        dp1 += __shfl_xor(dp1, 1);
        dp1 += __shfl_xor(dp1, 2);
        dp1 += __shfl_xor(dp1, 4);
        dp1 += __shfl_xor(dp1, 8);
        float d0 = 0.125f * w * dp0;               // (e^-0.25)^2 = 1/8
        float d1 = 0.125f * w * dp1;
        uint4 v4 = *(const uint4*)((const ushort*)vu + off);
        float vf[8] = { bflo(v4.x), bfhi(v4.x), bflo(v4.y), bfhi(v4.y),
                        bflo(v4.z), bfhi(v4.z), bflo(v4.w), bfhi(v4.w) };
        float nm0 = fmaxf(m0, d0), c0 = __expf(m0 - nm0), t0 = __expf(d0 - nm0);
        float nm1 = fmaxf(m1, d1), c1 = __expf(m1 - nm1), t1 = __expf(d1 - nm1);
        s0 = s0 * c0 + t0; m0 = nm0;
        s1 = s1 * c1 + t1; m1 = nm1;
        #pragma unroll
        for (int u = 0; u < 4; ++u) av[u] = av[u] * c0 + t0 * vf[u];
        #pragma unroll
        for (int u = 4; u < 8; ++u) av[u] = av[u] * c1 + t1 * vf[u];
    }

    float i0 = (p1 > p0) ? (1.f / s0) : 0.f;
    float i1 = (p1 > p0) ? (1.f / s1) : 0.f;
    float res[4];
    #pragma unroll
    for (int u = 0; u < 4; ++u) {
        float v = av[u] * i0 + av[u + 4] * i1;     // sum the group's two heads
        v += __shfl_xor(v, 16);                    // sum over the 4 groups (8 heads)
        v += __shfl_xor(v, 32);
        res[u] = v;
    }
    if (lane < 16) {
        #pragma unroll
        for (int u = 0; u < 4; ++u)
            out[(size_t)gr * E + u * 16 + lane] = res[u] + bu[u * 16 + lane];
    }
}

extern "C" void kernel_launch(void* const* d_in, const int* in_sizes, int n_in,
                              void* d_out, int out_size, void* d_ws, size_t ws_size,
                              hipStream_t stream) {
    const float* x        = (const float*)d_in[0];
    const float* Wq       = (const float*)d_in[1];
    const float* Wk       = (const float*)d_in[2];
    const float* Wv       = (const float*)d_in[3];
    const float* Wu       = (const float*)d_in[4];
    const float* bu       = (const float*)d_in[5];
    const float* means_p  = (const float*)d_in[6];
    const float* sigmas_p = (const float*)d_in[7];
    const int*   g_ints   = (const int*)d_in[8];
    const int*   l_offs   = (const int*)d_in[9];
    float* out = (float*)d_out;

    char* ws = (char*)d_ws;
    size_t o = 0;
    auto alloc = [&](size_t bytes) -> void* {
        void* p = ws + o;
        o += (bytes + 255) & ~(size_t)255;
        return p;
    };
    __hip_bfloat16* q   = (__hip_bfloat16*)alloc((size_t)B * T * NH * 2);
    __hip_bfloat16* kk  = (__hip_bfloat16*)alloc((size_t)B * T * NH * 2);
    __hip_bfloat16* vu  = (__hip_bfloat16*)alloc((size_t)B * T * NH * 2);
    ushort* xb    = (ushort*)alloc((size_t)B * T * E * 2);
    ushort* wfrag = (ushort*)alloc((size_t)3 * 32 * 2 * 64 * 8 * 2);
    float* Wvu    = (float*)alloc((size_t)E * NH * 4);
    float* meansf = (float*)alloc(KP * 2 * 4);
    float* sigt   = (float*)alloc(KP * 4);
    int*   idxrow = (int*)alloc((size_t)B * VS * 4);
    int*   idxcol = (int*)alloc((size_t)B * VS * 4);
    float* wts    = (float*)alloc((size_t)B * VS * 4);
    int*   lrank  = (int*)alloc((size_t)B * VS * 4);
    int*   dup    = (int*)alloc((size_t)B * VS * 4);
    float* colsum = (float*)alloc((size_t)B * KP * 4);
    int*   rowcnt = (int*)alloc((size_t)B * T * 4);
    int*   rowptr = (int*)alloc((size_t)B * (T + 1) * 4);
    int*   scol   = (int*)alloc((size_t)B * VS * 4);
    float* sw     = (float*)alloc((size_t)B * VS * 4);
    int*   hkey   = (int*)alloc((size_t)B * HSZ * 4);
    int*   hval   = (int*)alloc((size_t)B * HSZ * 4);
    int*   chist  = (int*)alloc((size_t)B * T * NCHUNK * 4);

    hipMemsetAsync(hkey, 0xFF, (size_t)B * HSZ * 4, stream);       // keys = -1
    hipMemsetAsync(hval, 0x7F, (size_t)B * HSZ * 4, stream);       // vals = big
    hipMemsetAsync(chist, 0, (size_t)B * T * NCHUNK * 4, stream);

    k_points<<<1, 256, 0, stream>>>(means_p, sigmas_p, meansf, sigt);
    k_wvu<<<(E * NH + 255) / 256, 256, 0, stream>>>(Wv, Wu, Wvu);
    k_prep_x<<<(B * T * E / 8) / 256, 256, 0, stream>>>(x, xb);
    k_prep_w<<<(3 * 32 * 2 * 64 + 255) / 256, 256, 0, stream>>>(Wq, Wk, Wvu, wfrag);
    k_build_idx<<<dim3(VS / 256, B), 256, 0, stream>>>(g_ints, l_offs, meansf, idxrow, idxcol, hkey, hval);
    k_local<<<dim3(NCHUNK, B), 256, 0, stream>>>(idxrow, idxcol, hkey, hval, lrank, dup, chist);
    k_chunkscan<<<B * T / 256, 256, 0, stream>>>(chist, rowcnt);
    k_colsum<<<dim3(KP, B), 256, 0, stream>>>(idxrow, idxcol, dup, meansf, sigt, colsum);
    k_weights<<<dim3(VS / 256, B), 256, 0, stream>>>(idxrow, idxcol, dup, meansf, sigt, colsum, wts);
    k_scan<<<B, 1024, 0, stream>>>(rowcnt, rowptr);
    k_scatter<<<dim3(VS / 256, B), 256, 0, stream>>>(idxrow, idxcol, wts, lrank, chist, rowptr, scol, sw);
    k_proj<<<dim3(B * T / 64, 3), 256, 0, stream>>>(xb, wfrag, q, kk, vu);
    k_attn<<<B * T / 4, 256, 0, stream>>>(q, kk, vu, rowptr, scol, sw, bu, out);
}